// Round 20
// baseline (201.731 us; speedup 1.0000x reference)
//
#include <hip/hip_runtime.h>
#include <math.h>

#define EPS 1e-5f

typedef float f32x16 __attribute__((ext_vector_type(16)));
typedef short short8 __attribute__((ext_vector_type(8)));

union U4S8 { uint4 u; short8 s; };

__device__ __forceinline__ float wave_sum64(float v) {
#pragma unroll
  for (int off = 32; off >= 1; off >>= 1) v += __shfl_xor(v, off, 64);
  return v;
}

__device__ __forceinline__ unsigned int bf16rne(float f) {
  unsigned int u = __float_as_uint(f);
  return (u + 0x7fffu + ((u >> 16) & 1u)) >> 16;
}
__device__ __forceinline__ unsigned int cvt_pk_bf16(float lo, float hi) {
  unsigned int r;
  asm("v_cvt_pk_bf16_f32 %0, %1, %2" : "=v"(r) : "v"(lo), "v"(hi));
  return r;
}

// K0: embed + qkv projection for layer 0, fused (round-16 kernel).
__global__ __launch_bounds__(192) void k_qkv0(
    const float* __restrict__ weather, const float* __restrict__ coords,
    const float* __restrict__ W_emb, const float* __restrict__ b_emb,
    const float* __restrict__ Wq, const float* __restrict__ bq,
    const float* __restrict__ gran, const int* __restrict__ tidx,
    float* __restrict__ x, unsigned int* __restrict__ qb,
    unsigned int* __restrict__ kbuf, unsigned short* __restrict__ vt) {
  int t = threadIdx.x;
  int row0 = blockIdx.x << 3;
  __shared__ float wrow[8][32];
  __shared__ float xs[8][64];
  for (int i = t; i < 256; i += 192) {
    int r = i >> 5, c2 = i & 31;
    if (c2 < 31) wrow[r][c2] = weather[(size_t)(row0 + r) * 31 + c2];
  }
  __syncthreads();
  int b = row0 >> 10;
  float lat = coords[b * 2 + 0] * 0.017453292519943295f;
  float lon = coords[b * 2 + 1] * 0.017453292519943295f;
  for (int idx = t; idx < 512; idx += 192) {
    int r = idx >> 6, e = idx & 63;
    int s = (row0 + r) & 1023;
    float acc = b_emb[e];
#pragma unroll
    for (int i = 0; i < 31; ++i) acc = fmaf(wrow[r][i], W_emb[i * 64 + e], acc);
    int g = e >> 2, rem = e & 3;
    float div = __expf(-0.5756462732485115f * (float)g);
    float pe;
    if (rem == 0)      pe = sinf((float)s * div);
    else if (rem == 1) pe = cosf((float)s * div);
    else if (rem == 2) pe = sinf(lat * div);
    else               pe = cosf(lon * div);
    float xv = acc + pe;
    xs[r][e] = xv;
    x[(size_t)(row0 + r) * 64 + e] = xv;
  }
  __syncthreads();
  float acc[8];
  float bias = bq[t];
#pragma unroll
  for (int r = 0; r < 8; ++r) acc[r] = bias;
#pragma unroll 4
  for (int k4 = 0; k4 < 16; ++k4) {
    float4 xv[8];
#pragma unroll
    for (int r = 0; r < 8; ++r) xv[r] = *(const float4*)(&xs[r][4 * k4]);
    float w0 = Wq[(4 * k4 + 0) * 192 + t];
    float w1 = Wq[(4 * k4 + 1) * 192 + t];
    float w2 = Wq[(4 * k4 + 2) * 192 + t];
    float w3 = Wq[(4 * k4 + 3) * 192 + t];
#pragma unroll
    for (int r = 0; r < 8; ++r) {
      acc[r] = fmaf(xv[r].x, w0, acc[r]);
      acc[r] = fmaf(xv[r].y, w1, acc[r]);
      acc[r] = fmaf(xv[r].z, w2, acc[r]);
      acc[r] = fmaf(xv[r].w, w3, acc[r]);
    }
  }
  int cq = t & 63;
  int hh = cq >> 3, hd = t & 7;
  int shi = (row0 & 1023) >> 3;
  int s2 = (b << 7) | shi;
  const float scl = 0.35355339059327373f;
#pragma unroll
  for (int r = 0; r < 8; ++r) {
    float o = acc[r];
    if (t < 128) o += gran[tidx[2 * r + 1] * 64 + cq];
    int bh = (r << 3) | hh;
    if (t < 64) {
      o *= scl;
      float nb = __shfl_down(o, 1, 64);
      if ((hd & 1) == 0)
        qb[((((size_t)bh << 10) | s2) << 2) + (hd >> 1)] =
            bf16rne(o) | (bf16rne(nb) << 16);
    } else if (t < 128) {
      float nb = __shfl_down(o, 1, 64);
      if ((hd & 1) == 0)
        kbuf[((((size_t)bh << 10) | s2) << 2) + (hd >> 1)] =
            bf16rne(o) | (bf16rne(nb) << 16);
    } else {
      vt[((size_t)bh << 13) + (hd << 10) + s2] = (unsigned short)bf16rne(o);
    }
  }
}

// K3 v2: MFMA flash attention, split-K x2 in-block (round-14 kernel).
__global__ __launch_bounds__(512, 2) void k_attn(
    const unsigned int* __restrict__ qb, const unsigned int* __restrict__ kbuf,
    const unsigned short* __restrict__ vt, float* __restrict__ ao) {
  int bh = blockIdx.x >> 3, chunk = blockIdx.x & 7;
  int slo = bh >> 3, h = bh & 7;
  int t = threadIdx.x;
  int l = t & 63, w = t >> 6;
  int grp = w >> 1, kh = w & 1;
  int lq = l & 31, g = l >> 5;
  bool kl = (l < 32);
  bool vl = (lq < 8);
  int q = (chunk << 7) + (grp << 5) + lq;

  U4S8 qf;
  qf.u = make_uint4(0, 0, 0, 0);
  if (kl) qf.u = *(const uint4*)(qb + ((((size_t)bh << 10) + q) << 2));

  const uint4* kp = (const uint4*)(kbuf + ((size_t)bh << 12));
  const unsigned short* vp = vt + ((size_t)bh << 13);

  f32x16 O, Z;
#pragma unroll
  for (int i = 0; i < 16; ++i) { O[i] = 0.f; Z[i] = 0.f; }
  float m = -1e30f, ls = 0.f;

  int kb0 = kh << 4;
  for (int kblk = kb0; kblk < kb0 + 16; ++kblk) {
    U4S8 af;
    af.u = make_uint4(0, 0, 0, 0);
    if (kl) af.u = kp[(kblk << 5) + lq];
    f32x16 S = __builtin_amdgcn_mfma_f32_32x32x16_bf16(af.s, qf.s, Z, 0, 0, 0);

    float mx = S[0];
#pragma unroll
    for (int i = 1; i < 16; ++i) mx = fmaxf(mx, S[i]);
    mx = fmaxf(mx, __shfl_xor(mx, 32, 64));
    if (mx > m + 8.f) {
      float esc = __expf(m - mx);
      ls *= esc;
      O *= esc;
      m = mx;
    }
    float p[16];
#pragma unroll
    for (int i = 0; i < 16; ++i) p[i] = __expf(S[i] - m);
    float s01 = (p[0] + p[1]) + (p[2] + p[3]);
    float s23 = (p[4] + p[5]) + (p[6] + p[7]);
    float s45 = (p[8] + p[9]) + (p[10] + p[11]);
    float s67 = (p[12] + p[13]) + (p[14] + p[15]);
    ls += (s01 + s23) + (s45 + s67);

    unsigned va = cvt_pk_bf16(p[0], p[1]),  vb = cvt_pk_bf16(p[2], p[3]);
    unsigned vc = cvt_pk_bf16(p[4], p[5]),  vd = cvt_pk_bf16(p[6], p[7]);
    unsigned ve = cvt_pk_bf16(p[8], p[9]),  vf = cvt_pk_bf16(p[10], p[11]);
    unsigned vg = cvt_pk_bf16(p[12], p[13]), vh = cvt_pk_bf16(p[14], p[15]);
    unsigned sa = __shfl_xor((int)va, 32, 64), sb = __shfl_xor((int)vb, 32, 64);
    unsigned sc = __shfl_xor((int)vc, 32, 64), sd = __shfl_xor((int)vd, 32, 64);
    unsigned se = __shfl_xor((int)ve, 32, 64), sf = __shfl_xor((int)vf, 32, 64);
    unsigned sg = __shfl_xor((int)vg, 32, 64), sh = __shfl_xor((int)vh, 32, 64);
    U4S8 b1, b2;
    b1.u.x = kl ? va : sc;  b1.u.y = kl ? vb : sd;
    b1.u.z = kl ? sa : vc;  b1.u.w = kl ? sb : vd;
    b2.u.x = kl ? ve : sg;  b2.u.y = kl ? vf : sh;
    b2.u.z = kl ? se : vg;  b2.u.w = kl ? sf : vh;

    U4S8 v1, v2;
    v1.u = make_uint4(0, 0, 0, 0);
    v2.u = make_uint4(0, 0, 0, 0);
    if (vl) {
      const unsigned short* vb8 = vp + (lq << 10) + (kblk << 5) + (g << 3);
      v1.u = *(const uint4*)vb8;
      v2.u = *(const uint4*)(vb8 + 16);
    }
    O = __builtin_amdgcn_mfma_f32_32x32x16_bf16(v1.s, b1.s, O, 0, 0, 0);
    O = __builtin_amdgcn_mfma_f32_32x32x16_bf16(v2.s, b2.s, O, 0, 0, 0);
  }

  ls += __shfl_xor(ls, 32, 64);

  __shared__ float pm[4][64], pl[4][64];
  __shared__ float po[4][64][4];
  if (kh == 0) {
    pm[grp][l] = m;
    pl[grp][l] = ls;
    *(float4*)(&po[grp][l][0]) = make_float4(O[0], O[1], O[2], O[3]);
  }
  __syncthreads();
  if (kh == 1) {
    float mA = pm[grp][l], lsA = pl[grp][l];
    float nm = fmaxf(m, mA);
    float wB = __expf(m - nm), wA = __expf(mA - nm);
    float4 oA = *(const float4*)(&po[grp][l][0]);
    float inv = 1.0f / (ls * wB + lsA * wA);
    int bq2 = q >> 7, sq = ((q & 127) << 3) | slo;
    float* op = ao + (((size_t)((bq2 << 10) | sq)) << 6) + (h << 3) + (g << 2);
    *(float4*)op = make_float4((O[0] * wB + oA.x * wA) * inv,
                               (O[1] * wB + oA.y * wA) * inv,
                               (O[2] * wB + oA.z * wA) * inv,
                               (O[3] * wB + oA.w * wA) * inv);
  }
}

// K4 v8: fused residual+LN+FFN+LN (+qkv emission) — OCCUPANCY-FIRST rebuild.
// Rounds 14-19 lesson: the 16-row/56KB-LDS design capped residency at 2
// blocks/CU (8-16 waves) and sat at ~42us regardless of micro-tweaks;
// round-13's full-occupancy version ran ~22us. Weights are L2-resident
// (~200MB aggregate = ~6us), so occupancy > reuse. New shape:
//   256 threads = 4 waves x 2 rows = 8 rows/block, grid 1024.
//   LDS ~10KB: aos[8][64] (ao -> x1 -> x_out staging, wave-private live
//   ranges) + h1s[8][256]. No W2 LDS staging (global fp32, TLP hides L2).
//   ONE barrier (before EMIT). (256,8) -> 64-VGPR cap; natural ~52 (R19).
template <bool EMIT>
__global__ __launch_bounds__(256, 8) void k_fused(
    const float* x_in, const float* __restrict__ ao,
    const float* __restrict__ Wo, const float* __restrict__ bo,
    const float* __restrict__ g1, const float* __restrict__ be1,
    const float* __restrict__ W1, const float* __restrict__ b1,
    const float* __restrict__ W2, const float* __restrict__ b2,
    const float* __restrict__ g2, const float* __restrict__ be2,
    const float* __restrict__ Wq, const float* __restrict__ bq,
    const float* __restrict__ gran, const int* __restrict__ tidx,
    unsigned int* __restrict__ qbo, unsigned int* __restrict__ kbo,
    unsigned short* __restrict__ vto, float* __restrict__ x_out) {
  int t = threadIdx.x, w = t >> 6, c = t & 63;
  int ws = w << 1;                  // 2 rows per wave
  int row_base = blockIdx.x << 3;   // 8 rows per block
  int row0 = row_base + ws;
  __shared__ float aos[8][64];      // ao -> x1 -> x_out staging
  __shared__ float h1s[8][256];
  float xin[2];
#pragma unroll
  for (int r = 0; r < 2; ++r) {
    aos[ws + r][c] = ao[(size_t)(row0 + r) * 64 + c];
    xin[r] = x_in[(size_t)(row0 + r) * 64 + c];
  }
  // ---- proj + residual + LN1 (wave-private rows; no barrier)
  float acc[2];
  float bov = bo[c];
#pragma unroll
  for (int r = 0; r < 2; ++r) acc[r] = bov;
#pragma unroll 4
  for (int k4 = 0; k4 < 16; ++k4) {
    float w0 = Wo[(4 * k4 + 0) * 64 + c], w1 = Wo[(4 * k4 + 1) * 64 + c];
    float w2 = Wo[(4 * k4 + 2) * 64 + c], w3 = Wo[(4 * k4 + 3) * 64 + c];
#pragma unroll
    for (int r = 0; r < 2; ++r) {
      float4 av = *(const float4*)(&aos[ws + r][4 * k4]);
      acc[r] = fmaf(av.x, w0, acc[r]);
      acc[r] = fmaf(av.y, w1, acc[r]);
      acc[r] = fmaf(av.z, w2, acc[r]);
      acc[r] = fmaf(av.w, w3, acc[r]);
    }
  }
  float g1v = g1[c], be1v = be1[c];
  float x1v[2];
#pragma unroll
  for (int r = 0; r < 2; ++r) {
    float y = acc[r] + xin[r];
    float s1 = wave_sum64(y), s2 = wave_sum64(y * y);
    float mean = s1 * 0.015625f, var = s2 * 0.015625f - mean * mean;
    x1v[r] = (y - mean) * rsqrtf(var + EPS) * g1v + be1v;
    aos[ws + r][c] = x1v[r];  // aos dead after proj; reuse for x1
  }
  // ---- ffn1 (x1 from aos, wave-private)
  float4 h[2];
  float4 b1v = *(const float4*)(b1 + 4 * c);
#pragma unroll
  for (int r = 0; r < 2; ++r) h[r] = b1v;
#pragma unroll 4
  for (int k4 = 0; k4 < 16; ++k4) {
    float4 w0 = *(const float4*)(W1 + (size_t)(4 * k4 + 0) * 256 + 4 * c);
    float4 w1 = *(const float4*)(W1 + (size_t)(4 * k4 + 1) * 256 + 4 * c);
    float4 w2 = *(const float4*)(W1 + (size_t)(4 * k4 + 2) * 256 + 4 * c);
    float4 w3 = *(const float4*)(W1 + (size_t)(4 * k4 + 3) * 256 + 4 * c);
#pragma unroll
    for (int r = 0; r < 2; ++r) {
      float4 xv = *(const float4*)(&aos[ws + r][4 * k4]);
      h[r].x = fmaf(xv.x, w0.x, h[r].x); h[r].y = fmaf(xv.x, w0.y, h[r].y);
      h[r].z = fmaf(xv.x, w0.z, h[r].z); h[r].w = fmaf(xv.x, w0.w, h[r].w);
      h[r].x = fmaf(xv.y, w1.x, h[r].x); h[r].y = fmaf(xv.y, w1.y, h[r].y);
      h[r].z = fmaf(xv.y, w1.z, h[r].z); h[r].w = fmaf(xv.y, w1.w, h[r].w);
      h[r].x = fmaf(xv.z, w2.x, h[r].x); h[r].y = fmaf(xv.z, w2.y, h[r].y);
      h[r].z = fmaf(xv.z, w2.z, h[r].z); h[r].w = fmaf(xv.z, w2.w, h[r].w);
      h[r].x = fmaf(xv.w, w3.x, h[r].x); h[r].y = fmaf(xv.w, w3.y, h[r].y);
      h[r].z = fmaf(xv.w, w3.z, h[r].z); h[r].w = fmaf(xv.w, w3.w, h[r].w);
    }
  }
#pragma unroll
  for (int r = 0; r < 2; ++r) {
    h[r].x = fmaxf(h[r].x, 0.f); h[r].y = fmaxf(h[r].y, 0.f);
    h[r].z = fmaxf(h[r].z, 0.f); h[r].w = fmaxf(h[r].w, 0.f);
    *(float4*)(&h1s[ws + r][4 * c]) = h[r];
  }
  // ---- ffn2 (h1 wave-private from LDS; W2 fp32 global) + LN2
  float acc2[2];
  float b2v = b2[c];
#pragma unroll
  for (int r = 0; r < 2; ++r) acc2[r] = b2v;
#pragma unroll 4
  for (int k4 = 0; k4 < 64; ++k4) {
    float w0 = W2[(size_t)(4 * k4 + 0) * 64 + c];
    float w1 = W2[(size_t)(4 * k4 + 1) * 64 + c];
    float w2 = W2[(size_t)(4 * k4 + 2) * 64 + c];
    float w3 = W2[(size_t)(4 * k4 + 3) * 64 + c];
#pragma unroll
    for (int r = 0; r < 2; ++r) {
      float4 hv = *(const float4*)(&h1s[ws + r][4 * k4]);
      acc2[r] = fmaf(hv.x, w0, acc2[r]);
      acc2[r] = fmaf(hv.y, w1, acc2[r]);
      acc2[r] = fmaf(hv.z, w2, acc2[r]);
      acc2[r] = fmaf(hv.w, w3, acc2[r]);
    }
  }
  float g2v = g2[c], be2v = be2[c];
#pragma unroll
  for (int r = 0; r < 2; ++r) {
    float y2 = acc2[r] + x1v[r];
    float t1 = wave_sum64(y2), t2 = wave_sum64(y2 * y2);
    float mean2 = t1 * 0.015625f, var2 = t2 * 0.015625f - mean2 * mean2;
    float xo = (y2 - mean2) * rsqrtf(var2 + EPS) * g2v + be2v;
    x_out[(size_t)(row0 + r) * 64 + c] = xo;
    aos[ws + r][c] = xo;  // stage for qkv phase (x1 dead now)
  }
  if (EMIT) {
    __syncthreads();  // all 8 x_out rows visible block-wide
    if (t < 192) {
      float qa[8];
      float bias = bq[t];
#pragma unroll
      for (int r = 0; r < 8; ++r) qa[r] = bias;
#pragma unroll 4
      for (int k4 = 0; k4 < 16; ++k4) {
        float w0 = Wq[(4 * k4 + 0) * 192 + t];
        float w1 = Wq[(4 * k4 + 1) * 192 + t];
        float w2v = Wq[(4 * k4 + 2) * 192 + t];
        float w3 = Wq[(4 * k4 + 3) * 192 + t];
#pragma unroll
        for (int r = 0; r < 8; ++r) {
          float4 av = *(const float4*)(&aos[r][4 * k4]);
          qa[r] = fmaf(av.x, w0, qa[r]);
          qa[r] = fmaf(av.y, w1, qa[r]);
          qa[r] = fmaf(av.z, w2v, qa[r]);
          qa[r] = fmaf(av.w, w3, qa[r]);
        }
      }
      int cq = t & 63, hh = cq >> 3, hd = t & 7;
      int bb = row_base >> 10;
      int s2 = (bb << 7) | ((row_base & 1023) >> 3);  // same for all 8 rows
      const float scl = 0.35355339059327373f;
#pragma unroll
      for (int r = 0; r < 8; ++r) {
        float o = qa[r];
        if (t < 128) o += gran[tidx[2 * r + 1] * 64 + cq];
        int bh = (r << 3) | hh;
        size_t base = ((size_t)(bh << 10)) | s2;
        if (t < 64) {
          o *= scl;
          float nb = __shfl_down(o, 1, 64);
          if ((hd & 1) == 0)
            qbo[(base << 2) + (hd >> 1)] = bf16rne(o) | (bf16rne(nb) << 16);
        } else if (t < 128) {
          float nb = __shfl_down(o, 1, 64);
          if ((hd & 1) == 0)
            kbo[(base << 2) + (hd >> 1)] = bf16rne(o) | (bf16rne(nb) << 16);
        } else {
          vto[((size_t)bh << 13) + (hd << 10) + s2] = (unsigned short)bf16rne(o);
        }
      }
    }
  }
}

// K6: out = x @ W_fc + b_fc
__global__ __launch_bounds__(256) void k_head(
    const float* __restrict__ x, const float* __restrict__ Wfc,
    const float* __restrict__ bfc, float* __restrict__ out) {
  int gid = blockIdx.x * 256 + threadIdx.x;
  int r = gid >> 5, o = gid & 31;
  if (o >= 31) return;
  float acc = bfc[o];
  const float* xr = x + (size_t)r * 64;
#pragma unroll
  for (int i = 0; i < 64; ++i) acc = fmaf(xr[i], Wfc[i * 31 + o], acc);
  out[(size_t)r * 31 + o] = acc;
}

extern "C" void kernel_launch(void* const* d_in, const int* in_sizes, int n_in,
                              void* d_out, int out_size, void* d_ws, size_t ws_size,
                              hipStream_t stream) {
  const float* weather = (const float*)d_in[0];
  const float* coords  = (const float*)d_in[1];
  const int*   tidx    = (const int*)d_in[2];
  const float* W_emb   = (const float*)d_in[3];
  const float* b_emb   = (const float*)d_in[4];
  const float* W_qkv   = (const float*)d_in[5];
  const float* b_qkv   = (const float*)d_in[6];
  const float* W_out   = (const float*)d_in[7];
  const float* b_out   = (const float*)d_in[8];
  const float* gran    = (const float*)d_in[9];
  const float* g1      = (const float*)d_in[10];
  const float* be1     = (const float*)d_in[11];
  const float* W1      = (const float*)d_in[12];
  const float* b1      = (const float*)d_in[13];
  const float* W2      = (const float*)d_in[14];
  const float* b2      = (const float*)d_in[15];
  const float* g2      = (const float*)d_in[16];
  const float* be2     = (const float*)d_in[17];
  const float* W_fc    = (const float*)d_in[18];
  const float* b_fc    = (const float*)d_in[19];
  float* out = (float*)d_out;

  // workspace: x(2MB) | qb(1MB) | kb(1MB) | vt(1MB) | ao(2MB) = 7MB
  float* x = (float*)d_ws;
  unsigned int* qbw = (unsigned int*)(x + 8192 * 64);
  unsigned int* kbw = qbw + 64 * 1024 * 4;
  unsigned short* vtw = (unsigned short*)(kbw + 64 * 1024 * 4);
  float* ao = (float*)(vtw + 64 * 8 * 1024);

  k_qkv0<<<1024, 192, 0, stream>>>(weather, coords, W_emb, b_emb,
                                   W_qkv, b_qkv, gran, tidx,
                                   x, qbw, kbw, vtw);
  for (int l = 0; l < 3; ++l) {
    k_attn<<<512, 512, 0, stream>>>(qbw, kbw, vtw, ao);
    if (l < 2) {
      k_fused<true><<<1024, 256, 0, stream>>>(
          x, ao, W_out + l * 64 * 64, b_out + l * 64,
          g1 + l * 64, be1 + l * 64, W1 + l * 64 * 256, b1 + l * 256,
          W2 + l * 256 * 64, b2 + l * 64, g2 + l * 64, be2 + l * 64,
          W_qkv + (l + 1) * 64 * 192, b_qkv + (l + 1) * 192,
          gran + (l + 1) * 31 * 64, tidx, qbw, kbw, vtw, x);
    } else {
      k_fused<false><<<1024, 256, 0, stream>>>(
          x, ao, W_out + l * 64 * 64, b_out + l * 64,
          g1 + l * 64, be1 + l * 64, W1 + l * 64 * 256, b1 + l * 256,
          W2 + l * 256 * 64, b2 + l * 64, g2 + l * 64, be2 + l * 64,
          nullptr, nullptr, nullptr, nullptr, nullptr, nullptr, nullptr, x);
    }
  }
  k_head<<<1024, 256, 0, stream>>>(x, W_fc, b_fc, out);
}

// Round 21
// 169.830 us; speedup vs baseline: 1.1878x; 1.1878x over previous
//
#include <hip/hip_runtime.h>
#include <math.h>

#define EPS 1e-5f

typedef float f32x16 __attribute__((ext_vector_type(16)));
typedef short short8 __attribute__((ext_vector_type(8)));

union U4S8 { uint4 u; short8 s; };

__device__ __forceinline__ float wave_sum64(float v) {
#pragma unroll
  for (int off = 32; off >= 1; off >>= 1) v += __shfl_xor(v, off, 64);
  return v;
}

__device__ __forceinline__ unsigned int bf16rne(float f) {
  unsigned int u = __float_as_uint(f);
  return (u + 0x7fffu + ((u >> 16) & 1u)) >> 16;
}
__device__ __forceinline__ unsigned int cvt_pk_bf16(float lo, float hi) {
  unsigned int r;
  asm("v_cvt_pk_bf16_f32 %0, %1, %2" : "=v"(r) : "v"(lo), "v"(hi));
  return r;
}

// K0: embed + qkv projection for layer 0, fused (round-16 kernel).
__global__ __launch_bounds__(192) void k_qkv0(
    const float* __restrict__ weather, const float* __restrict__ coords,
    const float* __restrict__ W_emb, const float* __restrict__ b_emb,
    const float* __restrict__ Wq, const float* __restrict__ bq,
    const float* __restrict__ gran, const int* __restrict__ tidx,
    float* __restrict__ x, unsigned int* __restrict__ qb,
    unsigned int* __restrict__ kbuf, unsigned short* __restrict__ vt) {
  int t = threadIdx.x;
  int row0 = blockIdx.x << 3;
  __shared__ float wrow[8][32];
  __shared__ float xs[8][64];
  for (int i = t; i < 256; i += 192) {
    int r = i >> 5, c2 = i & 31;
    if (c2 < 31) wrow[r][c2] = weather[(size_t)(row0 + r) * 31 + c2];
  }
  __syncthreads();
  int b = row0 >> 10;
  float lat = coords[b * 2 + 0] * 0.017453292519943295f;
  float lon = coords[b * 2 + 1] * 0.017453292519943295f;
  for (int idx = t; idx < 512; idx += 192) {
    int r = idx >> 6, e = idx & 63;
    int s = (row0 + r) & 1023;
    float acc = b_emb[e];
#pragma unroll
    for (int i = 0; i < 31; ++i) acc = fmaf(wrow[r][i], W_emb[i * 64 + e], acc);
    int g = e >> 2, rem = e & 3;
    float div = __expf(-0.5756462732485115f * (float)g);
    float pe;
    if (rem == 0)      pe = sinf((float)s * div);
    else if (rem == 1) pe = cosf((float)s * div);
    else if (rem == 2) pe = sinf(lat * div);
    else               pe = cosf(lon * div);
    float xv = acc + pe;
    xs[r][e] = xv;
    x[(size_t)(row0 + r) * 64 + e] = xv;
  }
  __syncthreads();
  float acc[8];
  float bias = bq[t];
#pragma unroll
  for (int r = 0; r < 8; ++r) acc[r] = bias;
#pragma unroll 4
  for (int k4 = 0; k4 < 16; ++k4) {
    float4 xv[8];
#pragma unroll
    for (int r = 0; r < 8; ++r) xv[r] = *(const float4*)(&xs[r][4 * k4]);
    float w0 = Wq[(4 * k4 + 0) * 192 + t];
    float w1 = Wq[(4 * k4 + 1) * 192 + t];
    float w2 = Wq[(4 * k4 + 2) * 192 + t];
    float w3 = Wq[(4 * k4 + 3) * 192 + t];
#pragma unroll
    for (int r = 0; r < 8; ++r) {
      acc[r] = fmaf(xv[r].x, w0, acc[r]);
      acc[r] = fmaf(xv[r].y, w1, acc[r]);
      acc[r] = fmaf(xv[r].z, w2, acc[r]);
      acc[r] = fmaf(xv[r].w, w3, acc[r]);
    }
  }
  int cq = t & 63;
  int hh = cq >> 3, hd = t & 7;
  int shi = (row0 & 1023) >> 3;
  int s2 = (b << 7) | shi;
  const float scl = 0.35355339059327373f;
#pragma unroll
  for (int r = 0; r < 8; ++r) {
    float o = acc[r];
    if (t < 128) o += gran[tidx[2 * r + 1] * 64 + cq];
    int bh = (r << 3) | hh;
    if (t < 64) {
      o *= scl;
      float nb = __shfl_down(o, 1, 64);
      if ((hd & 1) == 0)
        qb[((((size_t)bh << 10) | s2) << 2) + (hd >> 1)] =
            bf16rne(o) | (bf16rne(nb) << 16);
    } else if (t < 128) {
      float nb = __shfl_down(o, 1, 64);
      if ((hd & 1) == 0)
        kbuf[((((size_t)bh << 10) | s2) << 2) + (hd >> 1)] =
            bf16rne(o) | (bf16rne(nb) << 16);
    } else {
      vt[((size_t)bh << 13) + (hd << 10) + s2] = (unsigned short)bf16rne(o);
    }
  }
}

// K3 v2: MFMA flash attention, split-K x2 in-block (round-14 kernel).
__global__ __launch_bounds__(512, 2) void k_attn(
    const unsigned int* __restrict__ qb, const unsigned int* __restrict__ kbuf,
    const unsigned short* __restrict__ vt, float* __restrict__ ao) {
  int bh = blockIdx.x >> 3, chunk = blockIdx.x & 7;
  int slo = bh >> 3, h = bh & 7;
  int t = threadIdx.x;
  int l = t & 63, w = t >> 6;
  int grp = w >> 1, kh = w & 1;
  int lq = l & 31, g = l >> 5;
  bool kl = (l < 32);
  bool vl = (lq < 8);
  int q = (chunk << 7) + (grp << 5) + lq;

  U4S8 qf;
  qf.u = make_uint4(0, 0, 0, 0);
  if (kl) qf.u = *(const uint4*)(qb + ((((size_t)bh << 10) + q) << 2));

  const uint4* kp = (const uint4*)(kbuf + ((size_t)bh << 12));
  const unsigned short* vp = vt + ((size_t)bh << 13);

  f32x16 O, Z;
#pragma unroll
  for (int i = 0; i < 16; ++i) { O[i] = 0.f; Z[i] = 0.f; }
  float m = -1e30f, ls = 0.f;

  int kb0 = kh << 4;
  for (int kblk = kb0; kblk < kb0 + 16; ++kblk) {
    U4S8 af;
    af.u = make_uint4(0, 0, 0, 0);
    if (kl) af.u = kp[(kblk << 5) + lq];
    f32x16 S = __builtin_amdgcn_mfma_f32_32x32x16_bf16(af.s, qf.s, Z, 0, 0, 0);

    float mx = S[0];
#pragma unroll
    for (int i = 1; i < 16; ++i) mx = fmaxf(mx, S[i]);
    mx = fmaxf(mx, __shfl_xor(mx, 32, 64));
    if (mx > m + 8.f) {
      float esc = __expf(m - mx);
      ls *= esc;
      O *= esc;
      m = mx;
    }
    float p[16];
#pragma unroll
    for (int i = 0; i < 16; ++i) p[i] = __expf(S[i] - m);
    float s01 = (p[0] + p[1]) + (p[2] + p[3]);
    float s23 = (p[4] + p[5]) + (p[6] + p[7]);
    float s45 = (p[8] + p[9]) + (p[10] + p[11]);
    float s67 = (p[12] + p[13]) + (p[14] + p[15]);
    ls += (s01 + s23) + (s45 + s67);

    unsigned va = cvt_pk_bf16(p[0], p[1]),  vb = cvt_pk_bf16(p[2], p[3]);
    unsigned vc = cvt_pk_bf16(p[4], p[5]),  vd = cvt_pk_bf16(p[6], p[7]);
    unsigned ve = cvt_pk_bf16(p[8], p[9]),  vf = cvt_pk_bf16(p[10], p[11]);
    unsigned vg = cvt_pk_bf16(p[12], p[13]), vh = cvt_pk_bf16(p[14], p[15]);
    unsigned sa = __shfl_xor((int)va, 32, 64), sb = __shfl_xor((int)vb, 32, 64);
    unsigned sc = __shfl_xor((int)vc, 32, 64), sd = __shfl_xor((int)vd, 32, 64);
    unsigned se = __shfl_xor((int)ve, 32, 64), sf = __shfl_xor((int)vf, 32, 64);
    unsigned sg = __shfl_xor((int)vg, 32, 64), sh = __shfl_xor((int)vh, 32, 64);
    U4S8 b1, b2;
    b1.u.x = kl ? va : sc;  b1.u.y = kl ? vb : sd;
    b1.u.z = kl ? sa : vc;  b1.u.w = kl ? sb : vd;
    b2.u.x = kl ? ve : sg;  b2.u.y = kl ? vf : sh;
    b2.u.z = kl ? se : vg;  b2.u.w = kl ? sf : vh;

    U4S8 v1, v2;
    v1.u = make_uint4(0, 0, 0, 0);
    v2.u = make_uint4(0, 0, 0, 0);
    if (vl) {
      const unsigned short* vb8 = vp + (lq << 10) + (kblk << 5) + (g << 3);
      v1.u = *(const uint4*)vb8;
      v2.u = *(const uint4*)(vb8 + 16);
    }
    O = __builtin_amdgcn_mfma_f32_32x32x16_bf16(v1.s, b1.s, O, 0, 0, 0);
    O = __builtin_amdgcn_mfma_f32_32x32x16_bf16(v2.s, b2.s, O, 0, 0, 0);
  }

  ls += __shfl_xor(ls, 32, 64);

  __shared__ float pm[4][64], pl[4][64];
  __shared__ float po[4][64][4];
  if (kh == 0) {
    pm[grp][l] = m;
    pl[grp][l] = ls;
    *(float4*)(&po[grp][l][0]) = make_float4(O[0], O[1], O[2], O[3]);
  }
  __syncthreads();
  if (kh == 1) {
    float mA = pm[grp][l], lsA = pl[grp][l];
    float nm = fmaxf(m, mA);
    float wB = __expf(m - nm), wA = __expf(mA - nm);
    float4 oA = *(const float4*)(&po[grp][l][0]);
    float inv = 1.0f / (ls * wB + lsA * wA);
    int bq2 = q >> 7, sq = ((q & 127) << 3) | slo;
    float* op = ao + (((size_t)((bq2 << 10) | sq)) << 6) + (h << 3) + (g << 2);
    *(float4*)op = make_float4((O[0] * wB + oA.x * wA) * inv,
                               (O[1] * wB + oA.y * wA) * inv,
                               (O[2] * wB + oA.z * wA) * inv,
                               (O[3] * wB + oA.w * wA) * inv);
  }
}

// K4 v9: occupancy-first fused kernel (round-20 structure) with the clamp
// fixed. Round-20 lesson (3rd clamp spill this session): (256,8) = 64-VGPR
// budget made the allocator land at 32 VGPR WITH SPILLS (FETCH 2.9->6.0MB,
// WRITE 12->20MB, dur 42->55us). Natural liveness of this body is ~52
// (measured R19 under a 128 cap). Rule: cap one occupancy step ABOVE
// natural liveness -> (256,4) = 128-VGPR cap. Occupancy is then bounded
// by threads (8 blocks x 4 waves = 32 waves/CU, full), not VGPR.
template <bool EMIT>
__global__ __launch_bounds__(256, 4) void k_fused(
    const float* x_in, const float* __restrict__ ao,
    const float* __restrict__ Wo, const float* __restrict__ bo,
    const float* __restrict__ g1, const float* __restrict__ be1,
    const float* __restrict__ W1, const float* __restrict__ b1,
    const float* __restrict__ W2, const float* __restrict__ b2,
    const float* __restrict__ g2, const float* __restrict__ be2,
    const float* __restrict__ Wq, const float* __restrict__ bq,
    const float* __restrict__ gran, const int* __restrict__ tidx,
    unsigned int* __restrict__ qbo, unsigned int* __restrict__ kbo,
    unsigned short* __restrict__ vto, float* __restrict__ x_out) {
  int t = threadIdx.x, w = t >> 6, c = t & 63;
  int ws = w << 1;                  // 2 rows per wave
  int row_base = blockIdx.x << 3;   // 8 rows per block
  int row0 = row_base + ws;
  __shared__ float aos[8][64];      // ao -> x1 -> x_out staging
  __shared__ float h1s[8][256];
  float xin[2];
#pragma unroll
  for (int r = 0; r < 2; ++r) {
    aos[ws + r][c] = ao[(size_t)(row0 + r) * 64 + c];
    xin[r] = x_in[(size_t)(row0 + r) * 64 + c];
  }
  // ---- proj + residual + LN1 (wave-private rows; no barrier)
  float acc[2];
  float bov = bo[c];
#pragma unroll
  for (int r = 0; r < 2; ++r) acc[r] = bov;
#pragma unroll 4
  for (int k4 = 0; k4 < 16; ++k4) {
    float w0 = Wo[(4 * k4 + 0) * 64 + c], w1 = Wo[(4 * k4 + 1) * 64 + c];
    float w2 = Wo[(4 * k4 + 2) * 64 + c], w3 = Wo[(4 * k4 + 3) * 64 + c];
#pragma unroll
    for (int r = 0; r < 2; ++r) {
      float4 av = *(const float4*)(&aos[ws + r][4 * k4]);
      acc[r] = fmaf(av.x, w0, acc[r]);
      acc[r] = fmaf(av.y, w1, acc[r]);
      acc[r] = fmaf(av.z, w2, acc[r]);
      acc[r] = fmaf(av.w, w3, acc[r]);
    }
  }
  float g1v = g1[c], be1v = be1[c];
  float x1v[2];
#pragma unroll
  for (int r = 0; r < 2; ++r) {
    float y = acc[r] + xin[r];
    float s1 = wave_sum64(y), s2 = wave_sum64(y * y);
    float mean = s1 * 0.015625f, var = s2 * 0.015625f - mean * mean;
    x1v[r] = (y - mean) * rsqrtf(var + EPS) * g1v + be1v;
    aos[ws + r][c] = x1v[r];  // aos dead after proj; reuse for x1
  }
  // ---- ffn1 (x1 from aos, wave-private)
  float4 h[2];
  float4 b1v = *(const float4*)(b1 + 4 * c);
#pragma unroll
  for (int r = 0; r < 2; ++r) h[r] = b1v;
#pragma unroll 4
  for (int k4 = 0; k4 < 16; ++k4) {
    float4 w0 = *(const float4*)(W1 + (size_t)(4 * k4 + 0) * 256 + 4 * c);
    float4 w1 = *(const float4*)(W1 + (size_t)(4 * k4 + 1) * 256 + 4 * c);
    float4 w2 = *(const float4*)(W1 + (size_t)(4 * k4 + 2) * 256 + 4 * c);
    float4 w3 = *(const float4*)(W1 + (size_t)(4 * k4 + 3) * 256 + 4 * c);
#pragma unroll
    for (int r = 0; r < 2; ++r) {
      float4 xv = *(const float4*)(&aos[ws + r][4 * k4]);
      h[r].x = fmaf(xv.x, w0.x, h[r].x); h[r].y = fmaf(xv.x, w0.y, h[r].y);
      h[r].z = fmaf(xv.x, w0.z, h[r].z); h[r].w = fmaf(xv.x, w0.w, h[r].w);
      h[r].x = fmaf(xv.y, w1.x, h[r].x); h[r].y = fmaf(xv.y, w1.y, h[r].y);
      h[r].z = fmaf(xv.y, w1.z, h[r].z); h[r].w = fmaf(xv.y, w1.w, h[r].w);
      h[r].x = fmaf(xv.z, w2.x, h[r].x); h[r].y = fmaf(xv.z, w2.y, h[r].y);
      h[r].z = fmaf(xv.z, w2.z, h[r].z); h[r].w = fmaf(xv.z, w2.w, h[r].w);
      h[r].x = fmaf(xv.w, w3.x, h[r].x); h[r].y = fmaf(xv.w, w3.y, h[r].y);
      h[r].z = fmaf(xv.w, w3.z, h[r].z); h[r].w = fmaf(xv.w, w3.w, h[r].w);
    }
  }
#pragma unroll
  for (int r = 0; r < 2; ++r) {
    h[r].x = fmaxf(h[r].x, 0.f); h[r].y = fmaxf(h[r].y, 0.f);
    h[r].z = fmaxf(h[r].z, 0.f); h[r].w = fmaxf(h[r].w, 0.f);
    *(float4*)(&h1s[ws + r][4 * c]) = h[r];
  }
  // ---- ffn2 (h1 wave-private from LDS; W2 fp32 global) + LN2
  float acc2[2];
  float b2v = b2[c];
#pragma unroll
  for (int r = 0; r < 2; ++r) acc2[r] = b2v;
#pragma unroll 4
  for (int k4 = 0; k4 < 64; ++k4) {
    float w0 = W2[(size_t)(4 * k4 + 0) * 64 + c];
    float w1 = W2[(size_t)(4 * k4 + 1) * 64 + c];
    float w2 = W2[(size_t)(4 * k4 + 2) * 64 + c];
    float w3 = W2[(size_t)(4 * k4 + 3) * 64 + c];
#pragma unroll
    for (int r = 0; r < 2; ++r) {
      float4 hv = *(const float4*)(&h1s[ws + r][4 * k4]);
      acc2[r] = fmaf(hv.x, w0, acc2[r]);
      acc2[r] = fmaf(hv.y, w1, acc2[r]);
      acc2[r] = fmaf(hv.z, w2, acc2[r]);
      acc2[r] = fmaf(hv.w, w3, acc2[r]);
    }
  }
  float g2v = g2[c], be2v = be2[c];
#pragma unroll
  for (int r = 0; r < 2; ++r) {
    float y2 = acc2[r] + x1v[r];
    float t1 = wave_sum64(y2), t2 = wave_sum64(y2 * y2);
    float mean2 = t1 * 0.015625f, var2 = t2 * 0.015625f - mean2 * mean2;
    float xo = (y2 - mean2) * rsqrtf(var2 + EPS) * g2v + be2v;
    x_out[(size_t)(row0 + r) * 64 + c] = xo;
    aos[ws + r][c] = xo;  // stage for qkv phase (x1 dead now)
  }
  if (EMIT) {
    __syncthreads();  // all 8 x_out rows visible block-wide
    if (t < 192) {
      float qa[8];
      float bias = bq[t];
#pragma unroll
      for (int r = 0; r < 8; ++r) qa[r] = bias;
#pragma unroll 4
      for (int k4 = 0; k4 < 16; ++k4) {
        float w0 = Wq[(4 * k4 + 0) * 192 + t];
        float w1 = Wq[(4 * k4 + 1) * 192 + t];
        float w2v = Wq[(4 * k4 + 2) * 192 + t];
        float w3 = Wq[(4 * k4 + 3) * 192 + t];
#pragma unroll
        for (int r = 0; r < 8; ++r) {
          float4 av = *(const float4*)(&aos[r][4 * k4]);
          qa[r] = fmaf(av.x, w0, qa[r]);
          qa[r] = fmaf(av.y, w1, qa[r]);
          qa[r] = fmaf(av.z, w2v, qa[r]);
          qa[r] = fmaf(av.w, w3, qa[r]);
        }
      }
      int cq = t & 63, hh = cq >> 3, hd = t & 7;
      int bb = row_base >> 10;
      int s2 = (bb << 7) | ((row_base & 1023) >> 3);  // same for all 8 rows
      const float scl = 0.35355339059327373f;
#pragma unroll
      for (int r = 0; r < 8; ++r) {
        float o = qa[r];
        if (t < 128) o += gran[tidx[2 * r + 1] * 64 + cq];
        int bh = (r << 3) | hh;
        size_t base = ((size_t)(bh << 10)) | s2;
        if (t < 64) {
          o *= scl;
          float nb = __shfl_down(o, 1, 64);
          if ((hd & 1) == 0)
            qbo[(base << 2) + (hd >> 1)] = bf16rne(o) | (bf16rne(nb) << 16);
        } else if (t < 128) {
          float nb = __shfl_down(o, 1, 64);
          if ((hd & 1) == 0)
            kbo[(base << 2) + (hd >> 1)] = bf16rne(o) | (bf16rne(nb) << 16);
        } else {
          vto[((size_t)bh << 13) + (hd << 10) + s2] = (unsigned short)bf16rne(o);
        }
      }
    }
  }
}

// K6: out = x @ W_fc + b_fc
__global__ __launch_bounds__(256) void k_head(
    const float* __restrict__ x, const float* __restrict__ Wfc,
    const float* __restrict__ bfc, float* __restrict__ out) {
  int gid = blockIdx.x * 256 + threadIdx.x;
  int r = gid >> 5, o = gid & 31;
  if (o >= 31) return;
  float acc = bfc[o];
  const float* xr = x + (size_t)r * 64;
#pragma unroll
  for (int i = 0; i < 64; ++i) acc = fmaf(xr[i], Wfc[i * 31 + o], acc);
  out[(size_t)r * 31 + o] = acc;
}

extern "C" void kernel_launch(void* const* d_in, const int* in_sizes, int n_in,
                              void* d_out, int out_size, void* d_ws, size_t ws_size,
                              hipStream_t stream) {
  const float* weather = (const float*)d_in[0];
  const float* coords  = (const float*)d_in[1];
  const int*   tidx    = (const int*)d_in[2];
  const float* W_emb   = (const float*)d_in[3];
  const float* b_emb   = (const float*)d_in[4];
  const float* W_qkv   = (const float*)d_in[5];
  const float* b_qkv   = (const float*)d_in[6];
  const float* W_out   = (const float*)d_in[7];
  const float* b_out   = (const float*)d_in[8];
  const float* gran    = (const float*)d_in[9];
  const float* g1      = (const float*)d_in[10];
  const float* be1     = (const float*)d_in[11];
  const float* W1      = (const float*)d_in[12];
  const float* b1      = (const float*)d_in[13];
  const float* W2      = (const float*)d_in[14];
  const float* b2      = (const float*)d_in[15];
  const float* g2      = (const float*)d_in[16];
  const float* be2     = (const float*)d_in[17];
  const float* W_fc    = (const float*)d_in[18];
  const float* b_fc    = (const float*)d_in[19];
  float* out = (float*)d_out;

  // workspace: x(2MB) | qb(1MB) | kb(1MB) | vt(1MB) | ao(2MB) = 7MB
  float* x = (float*)d_ws;
  unsigned int* qbw = (unsigned int*)(x + 8192 * 64);
  unsigned int* kbw = qbw + 64 * 1024 * 4;
  unsigned short* vtw = (unsigned short*)(kbw + 64 * 1024 * 4);
  float* ao = (float*)(vtw + 64 * 8 * 1024);

  k_qkv0<<<1024, 192, 0, stream>>>(weather, coords, W_emb, b_emb,
                                   W_qkv, b_qkv, gran, tidx,
                                   x, qbw, kbw, vtw);
  for (int l = 0; l < 3; ++l) {
    k_attn<<<512, 512, 0, stream>>>(qbw, kbw, vtw, ao);
    if (l < 2) {
      k_fused<true><<<1024, 256, 0, stream>>>(
          x, ao, W_out + l * 64 * 64, b_out + l * 64,
          g1 + l * 64, be1 + l * 64, W1 + l * 64 * 256, b1 + l * 256,
          W2 + l * 256 * 64, b2 + l * 64, g2 + l * 64, be2 + l * 64,
          W_qkv + (l + 1) * 64 * 192, b_qkv + (l + 1) * 192,
          gran + (l + 1) * 31 * 64, tidx, qbw, kbw, vtw, x);
    } else {
      k_fused<false><<<1024, 256, 0, stream>>>(
          x, ao, W_out + l * 64 * 64, b_out + l * 64,
          g1 + l * 64, be1 + l * 64, W1 + l * 64 * 256, b1 + l * 256,
          W2 + l * 256 * 64, b2 + l * 64, g2 + l * 64, be2 + l * 64,
          nullptr, nullptr, nullptr, nullptr, nullptr, nullptr, nullptr, x);
    }
  }
  k_head<<<1024, 256, 0, stream>>>(x, W_fc, b_fc, out);
}

// Round 22
// 166.975 us; speedup vs baseline: 1.2082x; 1.0171x over previous
//
#include <hip/hip_runtime.h>
#include <math.h>

#define EPS 1e-5f

typedef float f32x16 __attribute__((ext_vector_type(16)));
typedef short short8 __attribute__((ext_vector_type(8)));

union U4S8 { uint4 u; short8 s; };

__device__ __forceinline__ float wave_sum64(float v) {
#pragma unroll
  for (int off = 32; off >= 1; off >>= 1) v += __shfl_xor(v, off, 64);
  return v;
}

__device__ __forceinline__ unsigned int bf16rne(float f) {
  unsigned int u = __float_as_uint(f);
  return (u + 0x7fffu + ((u >> 16) & 1u)) >> 16;
}
__device__ __forceinline__ unsigned int cvt_pk_bf16(float lo, float hi) {
  unsigned int r;
  asm("v_cvt_pk_bf16_f32 %0, %1, %2" : "=v"(r) : "v"(lo), "v"(hi));
  return r;
}

// K0: embed + qkv projection for layer 0, fused (round-16 kernel).
__global__ __launch_bounds__(192) void k_qkv0(
    const float* __restrict__ weather, const float* __restrict__ coords,
    const float* __restrict__ W_emb, const float* __restrict__ b_emb,
    const float* __restrict__ Wq, const float* __restrict__ bq,
    const float* __restrict__ gran, const int* __restrict__ tidx,
    float* __restrict__ x, unsigned int* __restrict__ qb,
    unsigned int* __restrict__ kbuf, unsigned short* __restrict__ vt) {
  int t = threadIdx.x;
  int row0 = blockIdx.x << 3;
  __shared__ float wrow[8][32];
  __shared__ float xs[8][64];
  for (int i = t; i < 256; i += 192) {
    int r = i >> 5, c2 = i & 31;
    if (c2 < 31) wrow[r][c2] = weather[(size_t)(row0 + r) * 31 + c2];
  }
  __syncthreads();
  int b = row0 >> 10;
  float lat = coords[b * 2 + 0] * 0.017453292519943295f;
  float lon = coords[b * 2 + 1] * 0.017453292519943295f;
  for (int idx = t; idx < 512; idx += 192) {
    int r = idx >> 6, e = idx & 63;
    int s = (row0 + r) & 1023;
    float acc = b_emb[e];
#pragma unroll
    for (int i = 0; i < 31; ++i) acc = fmaf(wrow[r][i], W_emb[i * 64 + e], acc);
    int g = e >> 2, rem = e & 3;
    float div = __expf(-0.5756462732485115f * (float)g);
    float pe;
    if (rem == 0)      pe = sinf((float)s * div);
    else if (rem == 1) pe = cosf((float)s * div);
    else if (rem == 2) pe = sinf(lat * div);
    else               pe = cosf(lon * div);
    float xv = acc + pe;
    xs[r][e] = xv;
    x[(size_t)(row0 + r) * 64 + e] = xv;
  }
  __syncthreads();
  float acc[8];
  float bias = bq[t];
#pragma unroll
  for (int r = 0; r < 8; ++r) acc[r] = bias;
#pragma unroll 4
  for (int k4 = 0; k4 < 16; ++k4) {
    float4 xv[8];
#pragma unroll
    for (int r = 0; r < 8; ++r) xv[r] = *(const float4*)(&xs[r][4 * k4]);
    float w0 = Wq[(4 * k4 + 0) * 192 + t];
    float w1 = Wq[(4 * k4 + 1) * 192 + t];
    float w2 = Wq[(4 * k4 + 2) * 192 + t];
    float w3 = Wq[(4 * k4 + 3) * 192 + t];
#pragma unroll
    for (int r = 0; r < 8; ++r) {
      acc[r] = fmaf(xv[r].x, w0, acc[r]);
      acc[r] = fmaf(xv[r].y, w1, acc[r]);
      acc[r] = fmaf(xv[r].z, w2, acc[r]);
      acc[r] = fmaf(xv[r].w, w3, acc[r]);
    }
  }
  int cq = t & 63;
  int hh = cq >> 3, hd = t & 7;
  int shi = (row0 & 1023) >> 3;
  int s2 = (b << 7) | shi;
  const float scl = 0.35355339059327373f;
#pragma unroll
  for (int r = 0; r < 8; ++r) {
    float o = acc[r];
    if (t < 128) o += gran[tidx[2 * r + 1] * 64 + cq];
    int bh = (r << 3) | hh;
    if (t < 64) {
      o *= scl;
      float nb = __shfl_down(o, 1, 64);
      if ((hd & 1) == 0)
        qb[((((size_t)bh << 10) | s2) << 2) + (hd >> 1)] =
            bf16rne(o) | (bf16rne(nb) << 16);
    } else if (t < 128) {
      float nb = __shfl_down(o, 1, 64);
      if ((hd & 1) == 0)
        kbuf[((((size_t)bh << 10) | s2) << 2) + (hd >> 1)] =
            bf16rne(o) | (bf16rne(nb) << 16);
    } else {
      vt[((size_t)bh << 13) + (hd << 10) + s2] = (unsigned short)bf16rne(o);
    }
  }
}

// K3 v2: MFMA flash attention, split-K x2 in-block (round-14 kernel).
__global__ __launch_bounds__(512, 2) void k_attn(
    const unsigned int* __restrict__ qb, const unsigned int* __restrict__ kbuf,
    const unsigned short* __restrict__ vt, float* __restrict__ ao) {
  int bh = blockIdx.x >> 3, chunk = blockIdx.x & 7;
  int slo = bh >> 3, h = bh & 7;
  int t = threadIdx.x;
  int l = t & 63, w = t >> 6;
  int grp = w >> 1, kh = w & 1;
  int lq = l & 31, g = l >> 5;
  bool kl = (l < 32);
  bool vl = (lq < 8);
  int q = (chunk << 7) + (grp << 5) + lq;

  U4S8 qf;
  qf.u = make_uint4(0, 0, 0, 0);
  if (kl) qf.u = *(const uint4*)(qb + ((((size_t)bh << 10) + q) << 2));

  const uint4* kp = (const uint4*)(kbuf + ((size_t)bh << 12));
  const unsigned short* vp = vt + ((size_t)bh << 13);

  f32x16 O, Z;
#pragma unroll
  for (int i = 0; i < 16; ++i) { O[i] = 0.f; Z[i] = 0.f; }
  float m = -1e30f, ls = 0.f;

  int kb0 = kh << 4;
  for (int kblk = kb0; kblk < kb0 + 16; ++kblk) {
    U4S8 af;
    af.u = make_uint4(0, 0, 0, 0);
    if (kl) af.u = kp[(kblk << 5) + lq];
    f32x16 S = __builtin_amdgcn_mfma_f32_32x32x16_bf16(af.s, qf.s, Z, 0, 0, 0);

    float mx = S[0];
#pragma unroll
    for (int i = 1; i < 16; ++i) mx = fmaxf(mx, S[i]);
    mx = fmaxf(mx, __shfl_xor(mx, 32, 64));
    if (mx > m + 8.f) {
      float esc = __expf(m - mx);
      ls *= esc;
      O *= esc;
      m = mx;
    }
    float p[16];
#pragma unroll
    for (int i = 0; i < 16; ++i) p[i] = __expf(S[i] - m);
    float s01 = (p[0] + p[1]) + (p[2] + p[3]);
    float s23 = (p[4] + p[5]) + (p[6] + p[7]);
    float s45 = (p[8] + p[9]) + (p[10] + p[11]);
    float s67 = (p[12] + p[13]) + (p[14] + p[15]);
    ls += (s01 + s23) + (s45 + s67);

    unsigned va = cvt_pk_bf16(p[0], p[1]),  vb = cvt_pk_bf16(p[2], p[3]);
    unsigned vc = cvt_pk_bf16(p[4], p[5]),  vd = cvt_pk_bf16(p[6], p[7]);
    unsigned ve = cvt_pk_bf16(p[8], p[9]),  vf = cvt_pk_bf16(p[10], p[11]);
    unsigned vg = cvt_pk_bf16(p[12], p[13]), vh = cvt_pk_bf16(p[14], p[15]);
    unsigned sa = __shfl_xor((int)va, 32, 64), sb = __shfl_xor((int)vb, 32, 64);
    unsigned sc = __shfl_xor((int)vc, 32, 64), sd = __shfl_xor((int)vd, 32, 64);
    unsigned se = __shfl_xor((int)ve, 32, 64), sf = __shfl_xor((int)vf, 32, 64);
    unsigned sg = __shfl_xor((int)vg, 32, 64), sh = __shfl_xor((int)vh, 32, 64);
    U4S8 b1, b2;
    b1.u.x = kl ? va : sc;  b1.u.y = kl ? vb : sd;
    b1.u.z = kl ? sa : vc;  b1.u.w = kl ? sb : vd;
    b2.u.x = kl ? ve : sg;  b2.u.y = kl ? vf : sh;
    b2.u.z = kl ? se : vg;  b2.u.w = kl ? sf : vh;

    U4S8 v1, v2;
    v1.u = make_uint4(0, 0, 0, 0);
    v2.u = make_uint4(0, 0, 0, 0);
    if (vl) {
      const unsigned short* vb8 = vp + (lq << 10) + (kblk << 5) + (g << 3);
      v1.u = *(const uint4*)vb8;
      v2.u = *(const uint4*)(vb8 + 16);
    }
    O = __builtin_amdgcn_mfma_f32_32x32x16_bf16(v1.s, b1.s, O, 0, 0, 0);
    O = __builtin_amdgcn_mfma_f32_32x32x16_bf16(v2.s, b2.s, O, 0, 0, 0);
  }

  ls += __shfl_xor(ls, 32, 64);

  __shared__ float pm[4][64], pl[4][64];
  __shared__ float po[4][64][4];
  if (kh == 0) {
    pm[grp][l] = m;
    pl[grp][l] = ls;
    *(float4*)(&po[grp][l][0]) = make_float4(O[0], O[1], O[2], O[3]);
  }
  __syncthreads();
  if (kh == 1) {
    float mA = pm[grp][l], lsA = pl[grp][l];
    float nm = fmaxf(m, mA);
    float wB = __expf(m - nm), wA = __expf(mA - nm);
    float4 oA = *(const float4*)(&po[grp][l][0]);
    float inv = 1.0f / (ls * wB + lsA * wA);
    int bq2 = q >> 7, sq = ((q & 127) << 3) | slo;
    float* op = ao + (((size_t)((bq2 << 10) | sq)) << 6) + (h << 3) + (g << 2);
    *(float4*)op = make_float4((O[0] * wB + oA.x * wA) * inv,
                               (O[1] * wB + oA.y * wA) * inv,
                               (O[2] * wB + oA.z * wA) * inv,
                               (O[3] * wB + oA.w * wA) * inv);
  }
}

// K4 v10: occupancy-first fused kernel (round-21 structure, (256,4) cap,
// VGPR ~52, no spills) + dispatch consolidation: the final-layer instance
// also computes the head (out = x_out @ W_fc + b_fc) from the aos staging
// buffer after the barrier — removes the k_head launch, its x re-read, and
// the l=2 x_out global write. Head math replicates k_head's exact
// k-ascending fma order -> bit-identical output.
template <bool EMIT, bool HEAD>
__global__ __launch_bounds__(256, 4) void k_fused(
    const float* x_in, const float* __restrict__ ao,
    const float* __restrict__ Wo, const float* __restrict__ bo,
    const float* __restrict__ g1, const float* __restrict__ be1,
    const float* __restrict__ W1, const float* __restrict__ b1,
    const float* __restrict__ W2, const float* __restrict__ b2,
    const float* __restrict__ g2, const float* __restrict__ be2,
    const float* __restrict__ Wq, const float* __restrict__ bq,
    const float* __restrict__ gran, const int* __restrict__ tidx,
    unsigned int* __restrict__ qbo, unsigned int* __restrict__ kbo,
    unsigned short* __restrict__ vto,
    const float* __restrict__ Wfc, const float* __restrict__ bfc,
    float* __restrict__ outp, float* __restrict__ x_out) {
  int t = threadIdx.x, w = t >> 6, c = t & 63;
  int ws = w << 1;                  // 2 rows per wave
  int row_base = blockIdx.x << 3;   // 8 rows per block
  int row0 = row_base + ws;
  __shared__ float aos[8][64];      // ao -> x1 -> x_out staging
  __shared__ float h1s[8][256];
  float xin[2];
#pragma unroll
  for (int r = 0; r < 2; ++r) {
    aos[ws + r][c] = ao[(size_t)(row0 + r) * 64 + c];
    xin[r] = x_in[(size_t)(row0 + r) * 64 + c];
  }
  // ---- proj + residual + LN1 (wave-private rows; no barrier)
  float acc[2];
  float bov = bo[c];
#pragma unroll
  for (int r = 0; r < 2; ++r) acc[r] = bov;
#pragma unroll 4
  for (int k4 = 0; k4 < 16; ++k4) {
    float w0 = Wo[(4 * k4 + 0) * 64 + c], w1 = Wo[(4 * k4 + 1) * 64 + c];
    float w2 = Wo[(4 * k4 + 2) * 64 + c], w3 = Wo[(4 * k4 + 3) * 64 + c];
#pragma unroll
    for (int r = 0; r < 2; ++r) {
      float4 av = *(const float4*)(&aos[ws + r][4 * k4]);
      acc[r] = fmaf(av.x, w0, acc[r]);
      acc[r] = fmaf(av.y, w1, acc[r]);
      acc[r] = fmaf(av.z, w2, acc[r]);
      acc[r] = fmaf(av.w, w3, acc[r]);
    }
  }
  float g1v = g1[c], be1v = be1[c];
  float x1v[2];
#pragma unroll
  for (int r = 0; r < 2; ++r) {
    float y = acc[r] + xin[r];
    float s1 = wave_sum64(y), s2 = wave_sum64(y * y);
    float mean = s1 * 0.015625f, var = s2 * 0.015625f - mean * mean;
    x1v[r] = (y - mean) * rsqrtf(var + EPS) * g1v + be1v;
    aos[ws + r][c] = x1v[r];  // aos dead after proj; reuse for x1
  }
  // ---- ffn1 (x1 from aos, wave-private)
  float4 h[2];
  float4 b1v = *(const float4*)(b1 + 4 * c);
#pragma unroll
  for (int r = 0; r < 2; ++r) h[r] = b1v;
#pragma unroll 4
  for (int k4 = 0; k4 < 16; ++k4) {
    float4 w0 = *(const float4*)(W1 + (size_t)(4 * k4 + 0) * 256 + 4 * c);
    float4 w1 = *(const float4*)(W1 + (size_t)(4 * k4 + 1) * 256 + 4 * c);
    float4 w2 = *(const float4*)(W1 + (size_t)(4 * k4 + 2) * 256 + 4 * c);
    float4 w3 = *(const float4*)(W1 + (size_t)(4 * k4 + 3) * 256 + 4 * c);
#pragma unroll
    for (int r = 0; r < 2; ++r) {
      float4 xv = *(const float4*)(&aos[ws + r][4 * k4]);
      h[r].x = fmaf(xv.x, w0.x, h[r].x); h[r].y = fmaf(xv.x, w0.y, h[r].y);
      h[r].z = fmaf(xv.x, w0.z, h[r].z); h[r].w = fmaf(xv.x, w0.w, h[r].w);
      h[r].x = fmaf(xv.y, w1.x, h[r].x); h[r].y = fmaf(xv.y, w1.y, h[r].y);
      h[r].z = fmaf(xv.y, w1.z, h[r].z); h[r].w = fmaf(xv.y, w1.w, h[r].w);
      h[r].x = fmaf(xv.z, w2.x, h[r].x); h[r].y = fmaf(xv.z, w2.y, h[r].y);
      h[r].z = fmaf(xv.z, w2.z, h[r].z); h[r].w = fmaf(xv.z, w2.w, h[r].w);
      h[r].x = fmaf(xv.w, w3.x, h[r].x); h[r].y = fmaf(xv.w, w3.y, h[r].y);
      h[r].z = fmaf(xv.w, w3.z, h[r].z); h[r].w = fmaf(xv.w, w3.w, h[r].w);
    }
  }
#pragma unroll
  for (int r = 0; r < 2; ++r) {
    h[r].x = fmaxf(h[r].x, 0.f); h[r].y = fmaxf(h[r].y, 0.f);
    h[r].z = fmaxf(h[r].z, 0.f); h[r].w = fmaxf(h[r].w, 0.f);
    *(float4*)(&h1s[ws + r][4 * c]) = h[r];
  }
  // ---- ffn2 (h1 wave-private from LDS; W2 fp32 global) + LN2
  float acc2[2];
  float b2v = b2[c];
#pragma unroll
  for (int r = 0; r < 2; ++r) acc2[r] = b2v;
#pragma unroll 4
  for (int k4 = 0; k4 < 64; ++k4) {
    float w0 = W2[(size_t)(4 * k4 + 0) * 64 + c];
    float w1 = W2[(size_t)(4 * k4 + 1) * 64 + c];
    float w2 = W2[(size_t)(4 * k4 + 2) * 64 + c];
    float w3 = W2[(size_t)(4 * k4 + 3) * 64 + c];
#pragma unroll
    for (int r = 0; r < 2; ++r) {
      float4 hv = *(const float4*)(&h1s[ws + r][4 * k4]);
      acc2[r] = fmaf(hv.x, w0, acc2[r]);
      acc2[r] = fmaf(hv.y, w1, acc2[r]);
      acc2[r] = fmaf(hv.z, w2, acc2[r]);
      acc2[r] = fmaf(hv.w, w3, acc2[r]);
    }
  }
  float g2v = g2[c], be2v = be2[c];
#pragma unroll
  for (int r = 0; r < 2; ++r) {
    float y2 = acc2[r] + x1v[r];
    float t1 = wave_sum64(y2), t2 = wave_sum64(y2 * y2);
    float mean2 = t1 * 0.015625f, var2 = t2 * 0.015625f - mean2 * mean2;
    float xo = (y2 - mean2) * rsqrtf(var2 + EPS) * g2v + be2v;
    if (!HEAD) x_out[(size_t)(row0 + r) * 64 + c] = xo;
    aos[ws + r][c] = xo;  // stage for qkv/head phase (x1 dead now)
  }
  if (EMIT) {
    __syncthreads();  // all 8 x_out rows visible block-wide
    if (t < 192) {
      float qa[8];
      float bias = bq[t];
#pragma unroll
      for (int r = 0; r < 8; ++r) qa[r] = bias;
#pragma unroll 4
      for (int k4 = 0; k4 < 16; ++k4) {
        float w0 = Wq[(4 * k4 + 0) * 192 + t];
        float w1 = Wq[(4 * k4 + 1) * 192 + t];
        float w2v = Wq[(4 * k4 + 2) * 192 + t];
        float w3 = Wq[(4 * k4 + 3) * 192 + t];
#pragma unroll
        for (int r = 0; r < 8; ++r) {
          float4 av = *(const float4*)(&aos[r][4 * k4]);
          qa[r] = fmaf(av.x, w0, qa[r]);
          qa[r] = fmaf(av.y, w1, qa[r]);
          qa[r] = fmaf(av.z, w2v, qa[r]);
          qa[r] = fmaf(av.w, w3, qa[r]);
        }
      }
      int cq = t & 63, hh = cq >> 3, hd = t & 7;
      int bb = row_base >> 10;
      int s2 = (bb << 7) | ((row_base & 1023) >> 3);  // same for all 8 rows
      const float scl = 0.35355339059327373f;
#pragma unroll
      for (int r = 0; r < 8; ++r) {
        float o = qa[r];
        if (t < 128) o += gran[tidx[2 * r + 1] * 64 + cq];
        int bh = (r << 3) | hh;
        size_t base = ((size_t)(bh << 10)) | s2;
        if (t < 64) {
          o *= scl;
          float nb = __shfl_down(o, 1, 64);
          if ((hd & 1) == 0)
            qbo[(base << 2) + (hd >> 1)] = bf16rne(o) | (bf16rne(nb) << 16);
        } else if (t < 128) {
          float nb = __shfl_down(o, 1, 64);
          if ((hd & 1) == 0)
            kbo[(base << 2) + (hd >> 1)] = bf16rne(o) | (bf16rne(nb) << 16);
        } else {
          vto[((size_t)bh << 13) + (hd << 10) + s2] = (unsigned short)bf16rne(o);
        }
      }
    }
  }
  if (HEAD) {
    __syncthreads();  // all 8 x_out rows visible block-wide
    int r = t >> 5, o = t & 31;  // 8 rows x 32 slots; o==31 idle
    if (o < 31) {
      float acc3 = bfc[o];
#pragma unroll 8
      for (int i = 0; i < 64; ++i)
        acc3 = fmaf(aos[r][i], Wfc[i * 31 + o], acc3);
      outp[(size_t)(row_base + r) * 31 + o] = acc3;
    }
  }
}

extern "C" void kernel_launch(void* const* d_in, const int* in_sizes, int n_in,
                              void* d_out, int out_size, void* d_ws, size_t ws_size,
                              hipStream_t stream) {
  const float* weather = (const float*)d_in[0];
  const float* coords  = (const float*)d_in[1];
  const int*   tidx    = (const int*)d_in[2];
  const float* W_emb   = (const float*)d_in[3];
  const float* b_emb   = (const float*)d_in[4];
  const float* W_qkv   = (const float*)d_in[5];
  const float* b_qkv   = (const float*)d_in[6];
  const float* W_out   = (const float*)d_in[7];
  const float* b_out   = (const float*)d_in[8];
  const float* gran    = (const float*)d_in[9];
  const float* g1      = (const float*)d_in[10];
  const float* be1     = (const float*)d_in[11];
  const float* W1      = (const float*)d_in[12];
  const float* b1      = (const float*)d_in[13];
  const float* W2      = (const float*)d_in[14];
  const float* b2      = (const float*)d_in[15];
  const float* g2      = (const float*)d_in[16];
  const float* be2     = (const float*)d_in[17];
  const float* W_fc    = (const float*)d_in[18];
  const float* b_fc    = (const float*)d_in[19];
  float* out = (float*)d_out;

  // workspace: x(2MB) | qb(1MB) | kb(1MB) | vt(1MB) | ao(2MB) = 7MB
  float* x = (float*)d_ws;
  unsigned int* qbw = (unsigned int*)(x + 8192 * 64);
  unsigned int* kbw = qbw + 64 * 1024 * 4;
  unsigned short* vtw = (unsigned short*)(kbw + 64 * 1024 * 4);
  float* ao = (float*)(vtw + 64 * 8 * 1024);

  k_qkv0<<<1024, 192, 0, stream>>>(weather, coords, W_emb, b_emb,
                                   W_qkv, b_qkv, gran, tidx,
                                   x, qbw, kbw, vtw);
  for (int l = 0; l < 3; ++l) {
    k_attn<<<512, 512, 0, stream>>>(qbw, kbw, vtw, ao);
    if (l < 2) {
      k_fused<true, false><<<1024, 256, 0, stream>>>(
          x, ao, W_out + l * 64 * 64, b_out + l * 64,
          g1 + l * 64, be1 + l * 64, W1 + l * 64 * 256, b1 + l * 256,
          W2 + l * 256 * 64, b2 + l * 64, g2 + l * 64, be2 + l * 64,
          W_qkv + (l + 1) * 64 * 192, b_qkv + (l + 1) * 192,
          gran + (l + 1) * 31 * 64, tidx, qbw, kbw, vtw,
          nullptr, nullptr, nullptr, x);
    } else {
      k_fused<false, true><<<1024, 256, 0, stream>>>(
          x, ao, W_out + l * 64 * 64, b_out + l * 64,
          g1 + l * 64, be1 + l * 64, W1 + l * 64 * 256, b1 + l * 256,
          W2 + l * 256 * 64, b2 + l * 64, g2 + l * 64, be2 + l * 64,
          nullptr, nullptr, nullptr, nullptr, nullptr, nullptr, nullptr,
          W_fc, b_fc, out, nullptr);
    }
  }
}

// Round 23
// 164.945 us; speedup vs baseline: 1.2230x; 1.0123x over previous
//
#include <hip/hip_runtime.h>
#include <math.h>

#define EPS 1e-5f

typedef float f32x16 __attribute__((ext_vector_type(16)));
typedef short short8 __attribute__((ext_vector_type(8)));

union U4S8 { uint4 u; short8 s; };

__device__ __forceinline__ float wave_sum64(float v) {
#pragma unroll
  for (int off = 32; off >= 1; off >>= 1) v += __shfl_xor(v, off, 64);
  return v;
}

__device__ __forceinline__ unsigned int bf16rne(float f) {
  unsigned int u = __float_as_uint(f);
  return (u + 0x7fffu + ((u >> 16) & 1u)) >> 16;
}
__device__ __forceinline__ float blo(unsigned int u) {
  return __uint_as_float(u << 16);
}
__device__ __forceinline__ float bhi(unsigned int u) {
  return __uint_as_float(u & 0xffff0000u);
}
__device__ __forceinline__ unsigned int cvt_pk_bf16(float lo, float hi) {
  unsigned int r;
  asm("v_cvt_pk_bf16_f32 %0, %1, %2" : "=v"(r) : "v"(lo), "v"(hi));
  return r;
}

// K-1: pack weights to bf16 pairs along k (runs once per launch, first).
// Layouts (pair p = k>>1, lo = even k, hi = odd k):
//   wbo[l][p][c]  (64x64 -> 32x64)    w1b[l][p][c]  (64x256 -> 32x256)
//   w2b[l][p][c]  (256x64 -> 128x64)  wqb[l-1][p][c] (64x192 -> 32x192, l=1,2)
__global__ __launch_bounds__(256) void k_prep(
    const float* __restrict__ Wo, const float* __restrict__ W1,
    const float* __restrict__ W2, const float* __restrict__ Wq,
    unsigned int* __restrict__ wbo, unsigned int* __restrict__ w1b,
    unsigned int* __restrict__ w2b, unsigned int* __restrict__ wqb) {
  int i = blockIdx.x * 256 + threadIdx.x;  // 24576 threads
  if (i < 6144) {
    int l = i >> 11, rem = i & 2047, p = rem >> 6, c = rem & 63;
    const float* s = Wo + l * 4096;
    wbo[i] = bf16rne(s[(2 * p) * 64 + c]) | (bf16rne(s[(2 * p + 1) * 64 + c]) << 16);
  }
  {
    int l = i / 8192, rem = i & 8191, p = rem >> 8, c = rem & 255;
    const float* s = W1 + (size_t)l * 16384;
    w1b[i] = bf16rne(s[(2 * p) * 256 + c]) | (bf16rne(s[(2 * p + 1) * 256 + c]) << 16);
  }
  {
    int l = i / 8192, rem = i & 8191, p = rem >> 6, c = rem & 63;
    const float* s = W2 + (size_t)l * 16384;
    w2b[i] = bf16rne(s[(2 * p) * 64 + c]) | (bf16rne(s[(2 * p + 1) * 64 + c]) << 16);
  }
  if (i < 12288) {
    int l = i / 6144, rem = i % 6144, p = rem / 192, c = rem % 192;
    const float* s = Wq + (size_t)(l + 1) * 12288;
    wqb[i] = bf16rne(s[(2 * p) * 192 + c]) | (bf16rne(s[(2 * p + 1) * 192 + c]) << 16);
  }
}

// K0: embed + qkv projection for layer 0, fused (round-16 kernel, fp32 Wq).
__global__ __launch_bounds__(192) void k_qkv0(
    const float* __restrict__ weather, const float* __restrict__ coords,
    const float* __restrict__ W_emb, const float* __restrict__ b_emb,
    const float* __restrict__ Wq, const float* __restrict__ bq,
    const float* __restrict__ gran, const int* __restrict__ tidx,
    float* __restrict__ x, unsigned int* __restrict__ qb,
    unsigned int* __restrict__ kbuf, unsigned short* __restrict__ vt) {
  int t = threadIdx.x;
  int row0 = blockIdx.x << 3;
  __shared__ float wrow[8][32];
  __shared__ float xs[8][64];
  for (int i = t; i < 256; i += 192) {
    int r = i >> 5, c2 = i & 31;
    if (c2 < 31) wrow[r][c2] = weather[(size_t)(row0 + r) * 31 + c2];
  }
  __syncthreads();
  int b = row0 >> 10;
  float lat = coords[b * 2 + 0] * 0.017453292519943295f;
  float lon = coords[b * 2 + 1] * 0.017453292519943295f;
  for (int idx = t; idx < 512; idx += 192) {
    int r = idx >> 6, e = idx & 63;
    int s = (row0 + r) & 1023;
    float acc = b_emb[e];
#pragma unroll
    for (int i = 0; i < 31; ++i) acc = fmaf(wrow[r][i], W_emb[i * 64 + e], acc);
    int g = e >> 2, rem = e & 3;
    float div = __expf(-0.5756462732485115f * (float)g);
    float pe;
    if (rem == 0)      pe = sinf((float)s * div);
    else if (rem == 1) pe = cosf((float)s * div);
    else if (rem == 2) pe = sinf(lat * div);
    else               pe = cosf(lon * div);
    float xv = acc + pe;
    xs[r][e] = xv;
    x[(size_t)(row0 + r) * 64 + e] = xv;
  }
  __syncthreads();
  float acc[8];
  float bias = bq[t];
#pragma unroll
  for (int r = 0; r < 8; ++r) acc[r] = bias;
#pragma unroll 4
  for (int k4 = 0; k4 < 16; ++k4) {
    float4 xv[8];
#pragma unroll
    for (int r = 0; r < 8; ++r) xv[r] = *(const float4*)(&xs[r][4 * k4]);
    float w0 = Wq[(4 * k4 + 0) * 192 + t];
    float w1 = Wq[(4 * k4 + 1) * 192 + t];
    float w2 = Wq[(4 * k4 + 2) * 192 + t];
    float w3 = Wq[(4 * k4 + 3) * 192 + t];
#pragma unroll
    for (int r = 0; r < 8; ++r) {
      acc[r] = fmaf(xv[r].x, w0, acc[r]);
      acc[r] = fmaf(xv[r].y, w1, acc[r]);
      acc[r] = fmaf(xv[r].z, w2, acc[r]);
      acc[r] = fmaf(xv[r].w, w3, acc[r]);
    }
  }
  int cq = t & 63;
  int hh = cq >> 3, hd = t & 7;
  int shi = (row0 & 1023) >> 3;
  int s2 = (b << 7) | shi;
  const float scl = 0.35355339059327373f;
#pragma unroll
  for (int r = 0; r < 8; ++r) {
    float o = acc[r];
    if (t < 128) o += gran[tidx[2 * r + 1] * 64 + cq];
    int bh = (r << 3) | hh;
    if (t < 64) {
      o *= scl;
      float nb = __shfl_down(o, 1, 64);
      if ((hd & 1) == 0)
        qb[((((size_t)bh << 10) | s2) << 2) + (hd >> 1)] =
            bf16rne(o) | (bf16rne(nb) << 16);
    } else if (t < 128) {
      float nb = __shfl_down(o, 1, 64);
      if ((hd & 1) == 0)
        kbuf[((((size_t)bh << 10) | s2) << 2) + (hd >> 1)] =
            bf16rne(o) | (bf16rne(nb) << 16);
    } else {
      vt[((size_t)bh << 13) + (hd << 10) + s2] = (unsigned short)bf16rne(o);
    }
  }
}

// K3 v2: MFMA flash attention, split-K x2 in-block (round-14 kernel).
__global__ __launch_bounds__(512, 2) void k_attn(
    const unsigned int* __restrict__ qb, const unsigned int* __restrict__ kbuf,
    const unsigned short* __restrict__ vt, float* __restrict__ ao) {
  int bh = blockIdx.x >> 3, chunk = blockIdx.x & 7;
  int slo = bh >> 3, h = bh & 7;
  int t = threadIdx.x;
  int l = t & 63, w = t >> 6;
  int grp = w >> 1, kh = w & 1;
  int lq = l & 31, g = l >> 5;
  bool kl = (l < 32);
  bool vl = (lq < 8);
  int q = (chunk << 7) + (grp << 5) + lq;

  U4S8 qf;
  qf.u = make_uint4(0, 0, 0, 0);
  if (kl) qf.u = *(const uint4*)(qb + ((((size_t)bh << 10) + q) << 2));

  const uint4* kp = (const uint4*)(kbuf + ((size_t)bh << 12));
  const unsigned short* vp = vt + ((size_t)bh << 13);

  f32x16 O, Z;
#pragma unroll
  for (int i = 0; i < 16; ++i) { O[i] = 0.f; Z[i] = 0.f; }
  float m = -1e30f, ls = 0.f;

  int kb0 = kh << 4;
  for (int kblk = kb0; kblk < kb0 + 16; ++kblk) {
    U4S8 af;
    af.u = make_uint4(0, 0, 0, 0);
    if (kl) af.u = kp[(kblk << 5) + lq];
    f32x16 S = __builtin_amdgcn_mfma_f32_32x32x16_bf16(af.s, qf.s, Z, 0, 0, 0);

    float mx = S[0];
#pragma unroll
    for (int i = 1; i < 16; ++i) mx = fmaxf(mx, S[i]);
    mx = fmaxf(mx, __shfl_xor(mx, 32, 64));
    if (mx > m + 8.f) {
      float esc = __expf(m - mx);
      ls *= esc;
      O *= esc;
      m = mx;
    }
    float p[16];
#pragma unroll
    for (int i = 0; i < 16; ++i) p[i] = __expf(S[i] - m);
    float s01 = (p[0] + p[1]) + (p[2] + p[3]);
    float s23 = (p[4] + p[5]) + (p[6] + p[7]);
    float s45 = (p[8] + p[9]) + (p[10] + p[11]);
    float s67 = (p[12] + p[13]) + (p[14] + p[15]);
    ls += (s01 + s23) + (s45 + s67);

    unsigned va = cvt_pk_bf16(p[0], p[1]),  vb = cvt_pk_bf16(p[2], p[3]);
    unsigned vc = cvt_pk_bf16(p[4], p[5]),  vd = cvt_pk_bf16(p[6], p[7]);
    unsigned ve = cvt_pk_bf16(p[8], p[9]),  vf = cvt_pk_bf16(p[10], p[11]);
    unsigned vg = cvt_pk_bf16(p[12], p[13]), vh = cvt_pk_bf16(p[14], p[15]);
    unsigned sa = __shfl_xor((int)va, 32, 64), sb = __shfl_xor((int)vb, 32, 64);
    unsigned sc = __shfl_xor((int)vc, 32, 64), sd = __shfl_xor((int)vd, 32, 64);
    unsigned se = __shfl_xor((int)ve, 32, 64), sf = __shfl_xor((int)vf, 32, 64);
    unsigned sg = __shfl_xor((int)vg, 32, 64), sh = __shfl_xor((int)vh, 32, 64);
    U4S8 b1, b2;
    b1.u.x = kl ? va : sc;  b1.u.y = kl ? vb : sd;
    b1.u.z = kl ? sa : vc;  b1.u.w = kl ? sb : vd;
    b2.u.x = kl ? ve : sg;  b2.u.y = kl ? vf : sh;
    b2.u.z = kl ? se : vg;  b2.u.w = kl ? sf : vh;

    U4S8 v1, v2;
    v1.u = make_uint4(0, 0, 0, 0);
    v2.u = make_uint4(0, 0, 0, 0);
    if (vl) {
      const unsigned short* vb8 = vp + (lq << 10) + (kblk << 5) + (g << 3);
      v1.u = *(const uint4*)vb8;
      v2.u = *(const uint4*)(vb8 + 16);
    }
    O = __builtin_amdgcn_mfma_f32_32x32x16_bf16(v1.s, b1.s, O, 0, 0, 0);
    O = __builtin_amdgcn_mfma_f32_32x32x16_bf16(v2.s, b2.s, O, 0, 0, 0);
  }

  ls += __shfl_xor(ls, 32, 64);

  __shared__ float pm[4][64], pl[4][64];
  __shared__ float po[4][64][4];
  if (kh == 0) {
    pm[grp][l] = m;
    pl[grp][l] = ls;
    *(float4*)(&po[grp][l][0]) = make_float4(O[0], O[1], O[2], O[3]);
  }
  __syncthreads();
  if (kh == 1) {
    float mA = pm[grp][l], lsA = pl[grp][l];
    float nm = fmaxf(m, mA);
    float wB = __expf(m - nm), wA = __expf(mA - nm);
    float4 oA = *(const float4*)(&po[grp][l][0]);
    float inv = 1.0f / (ls * wB + lsA * wA);
    int bq2 = q >> 7, sq = ((q & 127) << 3) | slo;
    float* op = ao + (((size_t)((bq2 << 10) | sq)) << 6) + (h << 3) + (g << 2);
    *(float4*)op = make_float4((O[0] * wB + oA.x * wA) * inv,
                               (O[1] * wB + oA.y * wA) * inv,
                               (O[2] * wB + oA.z * wA) * inv,
                               (O[3] * wB + oA.w * wA) * inv);
  }
}

// K4 v11: round-22 occupancy-first fused kernel, weights now packed bf16
// pairs from k_prep (round-22 analysis: kernel was L2-weight-BW bound —
// 4096 waves x 144KB = 590MB/dispatch ~= 17us at L2 ceiling; bf16 halves
// it). k-pair layout matches the existing k-ascending fma order exactly;
// prep writes are linear (both sides audited — R18 lesson). Biases and
// activations stay fp32.
template <bool EMIT, bool HEAD>
__global__ __launch_bounds__(256, 4) void k_fused(
    const float* x_in, const float* __restrict__ ao,
    const unsigned int* __restrict__ Wo, const float* __restrict__ bo,
    const float* __restrict__ g1, const float* __restrict__ be1,
    const unsigned int* __restrict__ W1, const float* __restrict__ b1,
    const unsigned int* __restrict__ W2, const float* __restrict__ b2,
    const float* __restrict__ g2, const float* __restrict__ be2,
    const unsigned int* __restrict__ Wq, const float* __restrict__ bq,
    const float* __restrict__ gran, const int* __restrict__ tidx,
    unsigned int* __restrict__ qbo, unsigned int* __restrict__ kbo,
    unsigned short* __restrict__ vto,
    const float* __restrict__ Wfc, const float* __restrict__ bfc,
    float* __restrict__ outp, float* __restrict__ x_out) {
  int t = threadIdx.x, w = t >> 6, c = t & 63;
  int ws = w << 1;                  // 2 rows per wave
  int row_base = blockIdx.x << 3;   // 8 rows per block
  int row0 = row_base + ws;
  __shared__ float aos[8][64];      // ao -> x1 -> x_out staging
  __shared__ float h1s[8][256];
  float xin[2];
#pragma unroll
  for (int r = 0; r < 2; ++r) {
    aos[ws + r][c] = ao[(size_t)(row0 + r) * 64 + c];
    xin[r] = x_in[(size_t)(row0 + r) * 64 + c];
  }
  // ---- proj + residual + LN1 (wave-private rows; no barrier)
  float acc[2];
  float bov = bo[c];
#pragma unroll
  for (int r = 0; r < 2; ++r) acc[r] = bov;
#pragma unroll 4
  for (int k4 = 0; k4 < 16; ++k4) {
    unsigned a = Wo[(2 * k4) * 64 + c], b = Wo[(2 * k4 + 1) * 64 + c];
    float w0 = blo(a), w1 = bhi(a), w2 = blo(b), w3 = bhi(b);
#pragma unroll
    for (int r = 0; r < 2; ++r) {
      float4 av = *(const float4*)(&aos[ws + r][4 * k4]);
      acc[r] = fmaf(av.x, w0, acc[r]);
      acc[r] = fmaf(av.y, w1, acc[r]);
      acc[r] = fmaf(av.z, w2, acc[r]);
      acc[r] = fmaf(av.w, w3, acc[r]);
    }
  }
  float g1v = g1[c], be1v = be1[c];
  float x1v[2];
#pragma unroll
  for (int r = 0; r < 2; ++r) {
    float y = acc[r] + xin[r];
    float s1 = wave_sum64(y), s2 = wave_sum64(y * y);
    float mean = s1 * 0.015625f, var = s2 * 0.015625f - mean * mean;
    x1v[r] = (y - mean) * rsqrtf(var + EPS) * g1v + be1v;
    aos[ws + r][c] = x1v[r];  // aos dead after proj; reuse for x1
  }
  // ---- ffn1 (x1 from aos, wave-private; W1 bf16 pairs)
  float4 h[2];
  float4 b1v = *(const float4*)(b1 + 4 * c);
#pragma unroll
  for (int r = 0; r < 2; ++r) h[r] = b1v;
#pragma unroll 4
  for (int k4 = 0; k4 < 16; ++k4) {
    uint4 A = *(const uint4*)(W1 + (2 * k4) * 256 + 4 * c);
    uint4 B = *(const uint4*)(W1 + (2 * k4 + 1) * 256 + 4 * c);
    float4 w0 = make_float4(blo(A.x), blo(A.y), blo(A.z), blo(A.w));  // k=4k4
    float4 w1 = make_float4(bhi(A.x), bhi(A.y), bhi(A.z), bhi(A.w));  // +1
    float4 w2 = make_float4(blo(B.x), blo(B.y), blo(B.z), blo(B.w));  // +2
    float4 w3 = make_float4(bhi(B.x), bhi(B.y), bhi(B.z), bhi(B.w));  // +3
#pragma unroll
    for (int r = 0; r < 2; ++r) {
      float4 xv = *(const float4*)(&aos[ws + r][4 * k4]);
      h[r].x = fmaf(xv.x, w0.x, h[r].x); h[r].y = fmaf(xv.x, w0.y, h[r].y);
      h[r].z = fmaf(xv.x, w0.z, h[r].z); h[r].w = fmaf(xv.x, w0.w, h[r].w);
      h[r].x = fmaf(xv.y, w1.x, h[r].x); h[r].y = fmaf(xv.y, w1.y, h[r].y);
      h[r].z = fmaf(xv.y, w1.z, h[r].z); h[r].w = fmaf(xv.y, w1.w, h[r].w);
      h[r].x = fmaf(xv.z, w2.x, h[r].x); h[r].y = fmaf(xv.z, w2.y, h[r].y);
      h[r].z = fmaf(xv.z, w2.z, h[r].z); h[r].w = fmaf(xv.z, w2.w, h[r].w);
      h[r].x = fmaf(xv.w, w3.x, h[r].x); h[r].y = fmaf(xv.w, w3.y, h[r].y);
      h[r].z = fmaf(xv.w, w3.z, h[r].z); h[r].w = fmaf(xv.w, w3.w, h[r].w);
    }
  }
#pragma unroll
  for (int r = 0; r < 2; ++r) {
    h[r].x = fmaxf(h[r].x, 0.f); h[r].y = fmaxf(h[r].y, 0.f);
    h[r].z = fmaxf(h[r].z, 0.f); h[r].w = fmaxf(h[r].w, 0.f);
    *(float4*)(&h1s[ws + r][4 * c]) = h[r];
  }
  // ---- ffn2 (h1 wave-private from LDS; W2 bf16 pairs) + LN2
  float acc2[2];
  float b2v = b2[c];
#pragma unroll
  for (int r = 0; r < 2; ++r) acc2[r] = b2v;
#pragma unroll 4
  for (int k4 = 0; k4 < 64; ++k4) {
    unsigned a = W2[(2 * k4) * 64 + c], b = W2[(2 * k4 + 1) * 64 + c];
    float w0 = blo(a), w1 = bhi(a), w2 = blo(b), w3 = bhi(b);
#pragma unroll
    for (int r = 0; r < 2; ++r) {
      float4 hv = *(const float4*)(&h1s[ws + r][4 * k4]);
      acc2[r] = fmaf(hv.x, w0, acc2[r]);
      acc2[r] = fmaf(hv.y, w1, acc2[r]);
      acc2[r] = fmaf(hv.z, w2, acc2[r]);
      acc2[r] = fmaf(hv.w, w3, acc2[r]);
    }
  }
  float g2v = g2[c], be2v = be2[c];
#pragma unroll
  for (int r = 0; r < 2; ++r) {
    float y2 = acc2[r] + x1v[r];
    float t1 = wave_sum64(y2), t2 = wave_sum64(y2 * y2);
    float mean2 = t1 * 0.015625f, var2 = t2 * 0.015625f - mean2 * mean2;
    float xo = (y2 - mean2) * rsqrtf(var2 + EPS) * g2v + be2v;
    if (!HEAD) x_out[(size_t)(row0 + r) * 64 + c] = xo;
    aos[ws + r][c] = xo;  // stage for qkv/head phase (x1 dead now)
  }
  if (EMIT) {
    __syncthreads();  // all 8 x_out rows visible block-wide
    if (t < 192) {
      float qa[8];
      float bias = bq[t];
#pragma unroll
      for (int r = 0; r < 8; ++r) qa[r] = bias;
#pragma unroll 4
      for (int k4 = 0; k4 < 16; ++k4) {
        unsigned a = Wq[(2 * k4) * 192 + t], b = Wq[(2 * k4 + 1) * 192 + t];
        float w0 = blo(a), w1 = bhi(a), w2v = blo(b), w3 = bhi(b);
#pragma unroll
        for (int r = 0; r < 8; ++r) {
          float4 av = *(const float4*)(&aos[r][4 * k4]);
          qa[r] = fmaf(av.x, w0, qa[r]);
          qa[r] = fmaf(av.y, w1, qa[r]);
          qa[r] = fmaf(av.z, w2v, qa[r]);
          qa[r] = fmaf(av.w, w3, qa[r]);
        }
      }
      int cq = t & 63, hh = cq >> 3, hd = t & 7;
      int bb = row_base >> 10;
      int s2 = (bb << 7) | ((row_base & 1023) >> 3);  // same for all 8 rows
      const float scl = 0.35355339059327373f;
#pragma unroll
      for (int r = 0; r < 8; ++r) {
        float o = qa[r];
        if (t < 128) o += gran[tidx[2 * r + 1] * 64 + cq];
        int bh = (r << 3) | hh;
        size_t base = ((size_t)(bh << 10)) | s2;
        if (t < 64) {
          o *= scl;
          float nb = __shfl_down(o, 1, 64);
          if ((hd & 1) == 0)
            qbo[(base << 2) + (hd >> 1)] = bf16rne(o) | (bf16rne(nb) << 16);
        } else if (t < 128) {
          float nb = __shfl_down(o, 1, 64);
          if ((hd & 1) == 0)
            kbo[(base << 2) + (hd >> 1)] = bf16rne(o) | (bf16rne(nb) << 16);
        } else {
          vto[((size_t)bh << 13) + (hd << 10) + s2] = (unsigned short)bf16rne(o);
        }
      }
    }
  }
  if (HEAD) {
    __syncthreads();  // all 8 x_out rows visible block-wide
    int r = t >> 5, o = t & 31;  // 8 rows x 32 slots; o==31 idle
    if (o < 31) {
      float acc3 = bfc[o];
#pragma unroll 8
      for (int i = 0; i < 64; ++i)
        acc3 = fmaf(aos[r][i], Wfc[i * 31 + o], acc3);
      outp[(size_t)(row_base + r) * 31 + o] = acc3;
    }
  }
}

extern "C" void kernel_launch(void* const* d_in, const int* in_sizes, int n_in,
                              void* d_out, int out_size, void* d_ws, size_t ws_size,
                              hipStream_t stream) {
  const float* weather = (const float*)d_in[0];
  const float* coords  = (const float*)d_in[1];
  const int*   tidx    = (const int*)d_in[2];
  const float* W_emb   = (const float*)d_in[3];
  const float* b_emb   = (const float*)d_in[4];
  const float* W_qkv   = (const float*)d_in[5];
  const float* b_qkv   = (const float*)d_in[6];
  const float* W_out   = (const float*)d_in[7];
  const float* b_out   = (const float*)d_in[8];
  const float* gran    = (const float*)d_in[9];
  const float* g1      = (const float*)d_in[10];
  const float* be1     = (const float*)d_in[11];
  const float* W1      = (const float*)d_in[12];
  const float* b1      = (const float*)d_in[13];
  const float* W2      = (const float*)d_in[14];
  const float* b2      = (const float*)d_in[15];
  const float* g2      = (const float*)d_in[16];
  const float* be2     = (const float*)d_in[17];
  const float* W_fc    = (const float*)d_in[18];
  const float* b_fc    = (const float*)d_in[19];
  float* out = (float*)d_out;

  // workspace: x(2MB) | qb(1MB) | kb(1MB) | vt(1MB) | ao(2MB) | packed W (264KB)
  float* x = (float*)d_ws;
  unsigned int* qbw = (unsigned int*)(x + 8192 * 64);
  unsigned int* kbw = qbw + 64 * 1024 * 4;
  unsigned short* vtw = (unsigned short*)(kbw + 64 * 1024 * 4);
  float* ao = (float*)(vtw + 64 * 8 * 1024);
  unsigned int* wbo = (unsigned int*)(ao + 8192 * 64);
  unsigned int* w1b = wbo + 6144;
  unsigned int* w2b = w1b + 24576;
  unsigned int* wqb = w2b + 24576;

  k_prep<<<96, 256, 0, stream>>>(W_out, W1, W2, W_qkv, wbo, w1b, w2b, wqb);
  k_qkv0<<<1024, 192, 0, stream>>>(weather, coords, W_emb, b_emb,
                                   W_qkv, b_qkv, gran, tidx,
                                   x, qbw, kbw, vtw);
  for (int l = 0; l < 3; ++l) {
    k_attn<<<512, 512, 0, stream>>>(qbw, kbw, vtw, ao);
    if (l < 2) {
      k_fused<true, false><<<1024, 256, 0, stream>>>(
          x, ao, wbo + l * 2048, b_out + l * 64,
          g1 + l * 64, be1 + l * 64, w1b + l * 8192, b1 + l * 256,
          w2b + l * 8192, b2 + l * 64, g2 + l * 64, be2 + l * 64,
          wqb + l * 6144, b_qkv + (l + 1) * 192,
          gran + (l + 1) * 31 * 64, tidx, qbw, kbw, vtw,
          nullptr, nullptr, nullptr, x);
    } else {
      k_fused<false, true><<<1024, 256, 0, stream>>>(
          x, ao, wbo + l * 2048, b_out + l * 64,
          g1 + l * 64, be1 + l * 64, w1b + l * 8192, b1 + l * 256,
          w2b + l * 8192, b2 + l * 64, g2 + l * 64, be2 + l * 64,
          nullptr, nullptr, nullptr, nullptr, nullptr, nullptr, nullptr,
          W_fc, b_fc, out, nullptr);
    }
  }
}

// Round 24
// 156.881 us; speedup vs baseline: 1.2859x; 1.0514x over previous
//
#include <hip/hip_runtime.h>
#include <math.h>

#define EPS 1e-5f

typedef float f32x16 __attribute__((ext_vector_type(16)));
typedef short short8 __attribute__((ext_vector_type(8)));

union U4S8 { uint4 u; short8 s; };

__device__ __forceinline__ float wave_sum64(float v) {
#pragma unroll
  for (int off = 32; off >= 1; off >>= 1) v += __shfl_xor(v, off, 64);
  return v;
}

__device__ __forceinline__ unsigned int bf16rne(float f) {
  unsigned int u = __float_as_uint(f);
  return (u + 0x7fffu + ((u >> 16) & 1u)) >> 16;
}
__device__ __forceinline__ float blo(unsigned int u) {
  return __uint_as_float(u << 16);
}
__device__ __forceinline__ float bhi(unsigned int u) {
  return __uint_as_float(u & 0xffff0000u);
}
__device__ __forceinline__ unsigned int cvt_pk_bf16(float lo, float hi) {
  unsigned int r;
  asm("v_cvt_pk_bf16_f32 %0, %1, %2" : "=v"(r) : "v"(lo), "v"(hi));
  return r;
}

// K0: embed + qkv projection for layer 0 + weight prep, fused.
// Prep (round-23's k_prep) folded in: gid < 67584 packs one bf16 weight
// pair; outputs are first consumed by k_fused AFTER attn l=0, so no
// ordering hazard. Saves one dispatch + gap.
__global__ __launch_bounds__(192) void k_qkv0(
    const float* __restrict__ weather, const float* __restrict__ coords,
    const float* __restrict__ W_emb, const float* __restrict__ b_emb,
    const float* __restrict__ Wq, const float* __restrict__ bq,
    const float* __restrict__ gran, const int* __restrict__ tidx,
    const float* __restrict__ Wo_f, const float* __restrict__ W1_f,
    const float* __restrict__ W2_f,
    float* __restrict__ x, unsigned int* __restrict__ qb,
    unsigned int* __restrict__ kbuf, unsigned short* __restrict__ vt,
    unsigned int* __restrict__ wbo, unsigned int* __restrict__ w1b,
    unsigned int* __restrict__ w2b, unsigned int* __restrict__ wqb) {
  int t = threadIdx.x;
  int row0 = blockIdx.x << 3;
  __shared__ float wrow[8][32];
  __shared__ float xs[8][64];
  for (int i = t; i < 256; i += 192) {
    int r = i >> 5, c2 = i & 31;
    if (c2 < 31) wrow[r][c2] = weather[(size_t)(row0 + r) * 31 + c2];
  }
  __syncthreads();
  int b = row0 >> 10;
  float lat = coords[b * 2 + 0] * 0.017453292519943295f;
  float lon = coords[b * 2 + 1] * 0.017453292519943295f;
  for (int idx = t; idx < 512; idx += 192) {
    int r = idx >> 6, e = idx & 63;
    int s = (row0 + r) & 1023;
    float acc = b_emb[e];
#pragma unroll
    for (int i = 0; i < 31; ++i) acc = fmaf(wrow[r][i], W_emb[i * 64 + e], acc);
    int g = e >> 2, rem = e & 3;
    float div = __expf(-0.5756462732485115f * (float)g);
    float pe;
    if (rem == 0)      pe = sinf((float)s * div);
    else if (rem == 1) pe = cosf((float)s * div);
    else if (rem == 2) pe = sinf(lat * div);
    else               pe = cosf(lon * div);
    float xv = acc + pe;
    xs[r][e] = xv;
    x[(size_t)(row0 + r) * 64 + e] = xv;
  }
  __syncthreads();
  float acc[8];
  float bias = bq[t];
#pragma unroll
  for (int r = 0; r < 8; ++r) acc[r] = bias;
#pragma unroll 4
  for (int k4 = 0; k4 < 16; ++k4) {
    float4 xv[8];
#pragma unroll
    for (int r = 0; r < 8; ++r) xv[r] = *(const float4*)(&xs[r][4 * k4]);
    float w0 = Wq[(4 * k4 + 0) * 192 + t];
    float w1 = Wq[(4 * k4 + 1) * 192 + t];
    float w2 = Wq[(4 * k4 + 2) * 192 + t];
    float w3 = Wq[(4 * k4 + 3) * 192 + t];
#pragma unroll
    for (int r = 0; r < 8; ++r) {
      acc[r] = fmaf(xv[r].x, w0, acc[r]);
      acc[r] = fmaf(xv[r].y, w1, acc[r]);
      acc[r] = fmaf(xv[r].z, w2, acc[r]);
      acc[r] = fmaf(xv[r].w, w3, acc[r]);
    }
  }
  int cq = t & 63;
  int hh = cq >> 3, hd = t & 7;
  int shi = (row0 & 1023) >> 3;
  int s2 = (b << 7) | shi;
  const float scl = 0.35355339059327373f;
#pragma unroll
  for (int r = 0; r < 8; ++r) {
    float o = acc[r];
    if (t < 128) o += gran[tidx[2 * r + 1] * 64 + cq];
    int bh = (r << 3) | hh;
    if (t < 64) {
      o *= scl;
      float nb = __shfl_down(o, 1, 64);
      if ((hd & 1) == 0)
        qb[((((size_t)bh << 10) | s2) << 2) + (hd >> 1)] =
            bf16rne(o) | (bf16rne(nb) << 16);
    } else if (t < 128) {
      float nb = __shfl_down(o, 1, 64);
      if ((hd & 1) == 0)
        kbuf[((((size_t)bh << 10) | s2) << 2) + (hd >> 1)] =
            bf16rne(o) | (bf16rne(nb) << 16);
    } else {
      vt[((size_t)bh << 13) + (hd << 10) + s2] = (unsigned short)bf16rne(o);
    }
  }
  // ---- weight-prep phase (one packed pair per thread, gid < 67584)
  int gid = blockIdx.x * 192 + t;
  if (gid < 6144) {
    int ll = gid >> 11, rem = gid & 2047, p = rem >> 6, c2 = rem & 63;
    const float* s = Wo_f + ll * 4096;
    wbo[gid] = bf16rne(s[(2 * p) * 64 + c2]) |
               (bf16rne(s[(2 * p + 1) * 64 + c2]) << 16);
  } else if (gid < 30720) {
    int i = gid - 6144;
    int ll = i / 8192, rem = i & 8191, p = rem >> 8, c2 = rem & 255;
    const float* s = W1_f + (size_t)ll * 16384;
    w1b[i] = bf16rne(s[(2 * p) * 256 + c2]) |
             (bf16rne(s[(2 * p + 1) * 256 + c2]) << 16);
  } else if (gid < 55296) {
    int i = gid - 30720;
    int ll = i / 8192, rem = i & 8191, p = rem >> 6, c2 = rem & 63;
    const float* s = W2_f + (size_t)ll * 16384;
    w2b[i] = bf16rne(s[(2 * p) * 64 + c2]) |
             (bf16rne(s[(2 * p + 1) * 64 + c2]) << 16);
  } else if (gid < 67584) {
    int i = gid - 55296;
    int ll = i / 6144, rem = i % 6144, p = rem / 192, c2 = rem % 192;
    const float* s = Wq + (size_t)(ll + 1) * 12288;
    wqb[i] = bf16rne(s[(2 * p) * 192 + c2]) |
             (bf16rne(s[(2 * p + 1) * 192 + c2]) << 16);
  }
}

// K3 v3: MFMA flash attention, split-K x4 in-block.
// Round-23 diagnosis: per-wave serial chain (MFMA -> 16-deep fmax -> exp
// -> pack -> 2 MFMA, ~175 dep-cycles) x 16 kblks at 4 waves/SIMD was the
// floor. Now 8 waves = 2 q-groups x 4 key-splits, 8 kblks each (serial
// path halves), grid 64 bh x 16 chunks = 1024 blocks -> 8192 waves =
// 8/SIMD (2x residency). 4-way partial merge via 12KB LDS — exact
// generalization of the proven 2-way merge.
__global__ __launch_bounds__(512, 2) void k_attn(
    const unsigned int* __restrict__ qb, const unsigned int* __restrict__ kbuf,
    const unsigned short* __restrict__ vt, float* __restrict__ ao) {
  int bh = blockIdx.x >> 4, chunk = blockIdx.x & 15;
  int slo = bh >> 3, h = bh & 7;
  int t = threadIdx.x;
  int l = t & 63, w = t >> 6;
  int grp = w >> 2, kh = w & 3;   // 2 q-groups x 4 key-splits
  int lq = l & 31, g = l >> 5;
  bool kl = (l < 32);
  bool vl = (lq < 8);
  int q = (chunk << 6) + (grp << 5) + lq;

  U4S8 qf;
  qf.u = make_uint4(0, 0, 0, 0);
  if (kl) qf.u = *(const uint4*)(qb + ((((size_t)bh << 10) + q) << 2));

  const uint4* kp = (const uint4*)(kbuf + ((size_t)bh << 12));
  const unsigned short* vp = vt + ((size_t)bh << 13);

  f32x16 O, Z;
#pragma unroll
  for (int i = 0; i < 16; ++i) { O[i] = 0.f; Z[i] = 0.f; }
  float m = -1e30f, ls = 0.f;

  int kb0 = kh << 3;
  for (int kblk = kb0; kblk < kb0 + 8; ++kblk) {
    U4S8 af;
    af.u = make_uint4(0, 0, 0, 0);
    if (kl) af.u = kp[(kblk << 5) + lq];
    f32x16 S = __builtin_amdgcn_mfma_f32_32x32x16_bf16(af.s, qf.s, Z, 0, 0, 0);

    float mx = S[0];
#pragma unroll
    for (int i = 1; i < 16; ++i) mx = fmaxf(mx, S[i]);
    mx = fmaxf(mx, __shfl_xor(mx, 32, 64));
    if (mx > m + 8.f) {
      float esc = __expf(m - mx);
      ls *= esc;
      O *= esc;
      m = mx;
    }
    float p[16];
#pragma unroll
    for (int i = 0; i < 16; ++i) p[i] = __expf(S[i] - m);
    float s01 = (p[0] + p[1]) + (p[2] + p[3]);
    float s23 = (p[4] + p[5]) + (p[6] + p[7]);
    float s45 = (p[8] + p[9]) + (p[10] + p[11]);
    float s67 = (p[12] + p[13]) + (p[14] + p[15]);
    ls += (s01 + s23) + (s45 + s67);

    unsigned va = cvt_pk_bf16(p[0], p[1]),  vb = cvt_pk_bf16(p[2], p[3]);
    unsigned vc = cvt_pk_bf16(p[4], p[5]),  vd = cvt_pk_bf16(p[6], p[7]);
    unsigned ve = cvt_pk_bf16(p[8], p[9]),  vf = cvt_pk_bf16(p[10], p[11]);
    unsigned vg = cvt_pk_bf16(p[12], p[13]), vh = cvt_pk_bf16(p[14], p[15]);
    unsigned sa = __shfl_xor((int)va, 32, 64), sb = __shfl_xor((int)vb, 32, 64);
    unsigned sc = __shfl_xor((int)vc, 32, 64), sd = __shfl_xor((int)vd, 32, 64);
    unsigned se = __shfl_xor((int)ve, 32, 64), sf = __shfl_xor((int)vf, 32, 64);
    unsigned sg = __shfl_xor((int)vg, 32, 64), sh = __shfl_xor((int)vh, 32, 64);
    U4S8 b1, b2;
    b1.u.x = kl ? va : sc;  b1.u.y = kl ? vb : sd;
    b1.u.z = kl ? sa : vc;  b1.u.w = kl ? sb : vd;
    b2.u.x = kl ? ve : sg;  b2.u.y = kl ? vf : sh;
    b2.u.z = kl ? se : vg;  b2.u.w = kl ? sf : vh;

    U4S8 v1, v2;
    v1.u = make_uint4(0, 0, 0, 0);
    v2.u = make_uint4(0, 0, 0, 0);
    if (vl) {
      const unsigned short* vb8 = vp + (lq << 10) + (kblk << 5) + (g << 3);
      v1.u = *(const uint4*)vb8;
      v2.u = *(const uint4*)(vb8 + 16);
    }
    O = __builtin_amdgcn_mfma_f32_32x32x16_bf16(v1.s, b1.s, O, 0, 0, 0);
    O = __builtin_amdgcn_mfma_f32_32x32x16_bf16(v2.s, b2.s, O, 0, 0, 0);
  }

  ls += __shfl_xor(ls, 32, 64);  // pair partials share m -> plain add

  // 4-way cross-wave merge (12KB LDS); wave kh==0 merges and writes.
  __shared__ float pm[2][4][64], pl[2][4][64];
  __shared__ float po[2][4][64][4];
  pm[grp][kh][l] = m;
  pl[grp][kh][l] = ls;
  *(float4*)(&po[grp][kh][l][0]) = make_float4(O[0], O[1], O[2], O[3]);
  __syncthreads();
  if (kh == 0) {
    float M = m;
#pragma unroll
    for (int j = 1; j < 4; ++j) M = fmaxf(M, pm[grp][j][l]);
    float w0 = __expf(m - M);
    float L = ls * w0;
    float o0 = O[0] * w0, o1 = O[1] * w0, o2 = O[2] * w0, o3 = O[3] * w0;
#pragma unroll
    for (int j = 1; j < 4; ++j) {
      float wj = __expf(pm[grp][j][l] - M);
      L = fmaf(pl[grp][j][l], wj, L);
      float4 oj = *(const float4*)(&po[grp][j][l][0]);
      o0 = fmaf(oj.x, wj, o0);
      o1 = fmaf(oj.y, wj, o1);
      o2 = fmaf(oj.z, wj, o2);
      o3 = fmaf(oj.w, wj, o3);
    }
    float inv = 1.0f / L;
    int bq2 = q >> 7, sq = ((q & 127) << 3) | slo;
    float* op = ao + (((size_t)((bq2 << 10) | sq)) << 6) + (h << 3) + (g << 2);
    *(float4*)op = make_float4(o0 * inv, o1 * inv, o2 * inv, o3 * inv);
  }
}

// K4 v11 (round-23 kernel, unchanged): occupancy-first fused layer with
// bf16-packed weights, optional next-layer qkv emission, optional head.
template <bool EMIT, bool HEAD>
__global__ __launch_bounds__(256, 4) void k_fused(
    const float* x_in, const float* __restrict__ ao,
    const unsigned int* __restrict__ Wo, const float* __restrict__ bo,
    const float* __restrict__ g1, const float* __restrict__ be1,
    const unsigned int* __restrict__ W1, const float* __restrict__ b1,
    const unsigned int* __restrict__ W2, const float* __restrict__ b2,
    const float* __restrict__ g2, const float* __restrict__ be2,
    const unsigned int* __restrict__ Wq, const float* __restrict__ bq,
    const float* __restrict__ gran, const int* __restrict__ tidx,
    unsigned int* __restrict__ qbo, unsigned int* __restrict__ kbo,
    unsigned short* __restrict__ vto,
    const float* __restrict__ Wfc, const float* __restrict__ bfc,
    float* __restrict__ outp, float* __restrict__ x_out) {
  int t = threadIdx.x, w = t >> 6, c = t & 63;
  int ws = w << 1;                  // 2 rows per wave
  int row_base = blockIdx.x << 3;   // 8 rows per block
  int row0 = row_base + ws;
  __shared__ float aos[8][64];      // ao -> x1 -> x_out staging
  __shared__ float h1s[8][256];
  float xin[2];
#pragma unroll
  for (int r = 0; r < 2; ++r) {
    aos[ws + r][c] = ao[(size_t)(row0 + r) * 64 + c];
    xin[r] = x_in[(size_t)(row0 + r) * 64 + c];
  }
  // ---- proj + residual + LN1 (wave-private rows; no barrier)
  float acc[2];
  float bov = bo[c];
#pragma unroll
  for (int r = 0; r < 2; ++r) acc[r] = bov;
#pragma unroll 4
  for (int k4 = 0; k4 < 16; ++k4) {
    unsigned a = Wo[(2 * k4) * 64 + c], b = Wo[(2 * k4 + 1) * 64 + c];
    float w0 = blo(a), w1 = bhi(a), w2 = blo(b), w3 = bhi(b);
#pragma unroll
    for (int r = 0; r < 2; ++r) {
      float4 av = *(const float4*)(&aos[ws + r][4 * k4]);
      acc[r] = fmaf(av.x, w0, acc[r]);
      acc[r] = fmaf(av.y, w1, acc[r]);
      acc[r] = fmaf(av.z, w2, acc[r]);
      acc[r] = fmaf(av.w, w3, acc[r]);
    }
  }
  float g1v = g1[c], be1v = be1[c];
  float x1v[2];
#pragma unroll
  for (int r = 0; r < 2; ++r) {
    float y = acc[r] + xin[r];
    float s1 = wave_sum64(y), s2 = wave_sum64(y * y);
    float mean = s1 * 0.015625f, var = s2 * 0.015625f - mean * mean;
    x1v[r] = (y - mean) * rsqrtf(var + EPS) * g1v + be1v;
    aos[ws + r][c] = x1v[r];  // aos dead after proj; reuse for x1
  }
  // ---- ffn1 (x1 from aos, wave-private; W1 bf16 pairs)
  float4 h[2];
  float4 b1v = *(const float4*)(b1 + 4 * c);
#pragma unroll
  for (int r = 0; r < 2; ++r) h[r] = b1v;
#pragma unroll 4
  for (int k4 = 0; k4 < 16; ++k4) {
    uint4 A = *(const uint4*)(W1 + (2 * k4) * 256 + 4 * c);
    uint4 B = *(const uint4*)(W1 + (2 * k4 + 1) * 256 + 4 * c);
    float4 w0 = make_float4(blo(A.x), blo(A.y), blo(A.z), blo(A.w));
    float4 w1 = make_float4(bhi(A.x), bhi(A.y), bhi(A.z), bhi(A.w));
    float4 w2 = make_float4(blo(B.x), blo(B.y), blo(B.z), blo(B.w));
    float4 w3 = make_float4(bhi(B.x), bhi(B.y), bhi(B.z), bhi(B.w));
#pragma unroll
    for (int r = 0; r < 2; ++r) {
      float4 xv = *(const float4*)(&aos[ws + r][4 * k4]);
      h[r].x = fmaf(xv.x, w0.x, h[r].x); h[r].y = fmaf(xv.x, w0.y, h[r].y);
      h[r].z = fmaf(xv.x, w0.z, h[r].z); h[r].w = fmaf(xv.x, w0.w, h[r].w);
      h[r].x = fmaf(xv.y, w1.x, h[r].x); h[r].y = fmaf(xv.y, w1.y, h[r].y);
      h[r].z = fmaf(xv.y, w1.z, h[r].z); h[r].w = fmaf(xv.y, w1.w, h[r].w);
      h[r].x = fmaf(xv.z, w2.x, h[r].x); h[r].y = fmaf(xv.z, w2.y, h[r].y);
      h[r].z = fmaf(xv.z, w2.z, h[r].z); h[r].w = fmaf(xv.z, w2.w, h[r].w);
      h[r].x = fmaf(xv.w, w3.x, h[r].x); h[r].y = fmaf(xv.w, w3.y, h[r].y);
      h[r].z = fmaf(xv.w, w3.z, h[r].z); h[r].w = fmaf(xv.w, w3.w, h[r].w);
    }
  }
#pragma unroll
  for (int r = 0; r < 2; ++r) {
    h[r].x = fmaxf(h[r].x, 0.f); h[r].y = fmaxf(h[r].y, 0.f);
    h[r].z = fmaxf(h[r].z, 0.f); h[r].w = fmaxf(h[r].w, 0.f);
    *(float4*)(&h1s[ws + r][4 * c]) = h[r];
  }
  // ---- ffn2 (h1 wave-private from LDS; W2 bf16 pairs) + LN2
  float acc2[2];
  float b2v = b2[c];
#pragma unroll
  for (int r = 0; r < 2; ++r) acc2[r] = b2v;
#pragma unroll 4
  for (int k4 = 0; k4 < 64; ++k4) {
    unsigned a = W2[(2 * k4) * 64 + c], b = W2[(2 * k4 + 1) * 64 + c];
    float w0 = blo(a), w1 = bhi(a), w2 = blo(b), w3 = bhi(b);
#pragma unroll
    for (int r = 0; r < 2; ++r) {
      float4 hv = *(const float4*)(&h1s[ws + r][4 * k4]);
      acc2[r] = fmaf(hv.x, w0, acc2[r]);
      acc2[r] = fmaf(hv.y, w1, acc2[r]);
      acc2[r] = fmaf(hv.z, w2, acc2[r]);
      acc2[r] = fmaf(hv.w, w3, acc2[r]);
    }
  }
  float g2v = g2[c], be2v = be2[c];
#pragma unroll
  for (int r = 0; r < 2; ++r) {
    float y2 = acc2[r] + x1v[r];
    float t1 = wave_sum64(y2), t2 = wave_sum64(y2 * y2);
    float mean2 = t1 * 0.015625f, var2 = t2 * 0.015625f - mean2 * mean2;
    float xo = (y2 - mean2) * rsqrtf(var2 + EPS) * g2v + be2v;
    if (!HEAD) x_out[(size_t)(row0 + r) * 64 + c] = xo;
    aos[ws + r][c] = xo;  // stage for qkv/head phase (x1 dead now)
  }
  if (EMIT) {
    __syncthreads();  // all 8 x_out rows visible block-wide
    if (t < 192) {
      float qa[8];
      float bias = bq[t];
#pragma unroll
      for (int r = 0; r < 8; ++r) qa[r] = bias;
#pragma unroll 4
      for (int k4 = 0; k4 < 16; ++k4) {
        unsigned a = Wq[(2 * k4) * 192 + t], b = Wq[(2 * k4 + 1) * 192 + t];
        float w0 = blo(a), w1 = bhi(a), w2v = blo(b), w3 = bhi(b);
#pragma unroll
        for (int r = 0; r < 8; ++r) {
          float4 av = *(const float4*)(&aos[r][4 * k4]);
          qa[r] = fmaf(av.x, w0, qa[r]);
          qa[r] = fmaf(av.y, w1, qa[r]);
          qa[r] = fmaf(av.z, w2v, qa[r]);
          qa[r] = fmaf(av.w, w3, qa[r]);
        }
      }
      int cq = t & 63, hh = cq >> 3, hd = t & 7;
      int bb = row_base >> 10;
      int s2 = (bb << 7) | ((row_base & 1023) >> 3);  // same for all 8 rows
      const float scl = 0.35355339059327373f;
#pragma unroll
      for (int r = 0; r < 8; ++r) {
        float o = qa[r];
        if (t < 128) o += gran[tidx[2 * r + 1] * 64 + cq];
        int bh = (r << 3) | hh;
        size_t base = ((size_t)(bh << 10)) | s2;
        if (t < 64) {
          o *= scl;
          float nb = __shfl_down(o, 1, 64);
          if ((hd & 1) == 0)
            qbo[(base << 2) + (hd >> 1)] = bf16rne(o) | (bf16rne(nb) << 16);
        } else if (t < 128) {
          float nb = __shfl_down(o, 1, 64);
          if ((hd & 1) == 0)
            kbo[(base << 2) + (hd >> 1)] = bf16rne(o) | (bf16rne(nb) << 16);
        } else {
          vto[((size_t)bh << 13) + (hd << 10) + s2] = (unsigned short)bf16rne(o);
        }
      }
    }
  }
  if (HEAD) {
    __syncthreads();  // all 8 x_out rows visible block-wide
    int r = t >> 5, o = t & 31;  // 8 rows x 32 slots; o==31 idle
    if (o < 31) {
      float acc3 = bfc[o];
#pragma unroll 8
      for (int i = 0; i < 64; ++i)
        acc3 = fmaf(aos[r][i], Wfc[i * 31 + o], acc3);
      outp[(size_t)(row_base + r) * 31 + o] = acc3;
    }
  }
}

extern "C" void kernel_launch(void* const* d_in, const int* in_sizes, int n_in,
                              void* d_out, int out_size, void* d_ws, size_t ws_size,
                              hipStream_t stream) {
  const float* weather = (const float*)d_in[0];
  const float* coords  = (const float*)d_in[1];
  const int*   tidx    = (const int*)d_in[2];
  const float* W_emb   = (const float*)d_in[3];
  const float* b_emb   = (const float*)d_in[4];
  const float* W_qkv   = (const float*)d_in[5];
  const float* b_qkv   = (const float*)d_in[6];
  const float* W_out   = (const float*)d_in[7];
  const float* b_out   = (const float*)d_in[8];
  const float* gran    = (const float*)d_in[9];
  const float* g1      = (const float*)d_in[10];
  const float* be1     = (const float*)d_in[11];
  const float* W1      = (const float*)d_in[12];
  const float* b1      = (const float*)d_in[13];
  const float* W2      = (const float*)d_in[14];
  const float* b2      = (const float*)d_in[15];
  const float* g2      = (const float*)d_in[16];
  const float* be2     = (const float*)d_in[17];
  const float* W_fc    = (const float*)d_in[18];
  const float* b_fc    = (const float*)d_in[19];
  float* out = (float*)d_out;

  // workspace: x(2MB) | qb(1MB) | kb(1MB) | vt(1MB) | ao(2MB) | packed W
  float* x = (float*)d_ws;
  unsigned int* qbw = (unsigned int*)(x + 8192 * 64);
  unsigned int* kbw = qbw + 64 * 1024 * 4;
  unsigned short* vtw = (unsigned short*)(kbw + 64 * 1024 * 4);
  float* ao = (float*)(vtw + 64 * 8 * 1024);
  unsigned int* wbo = (unsigned int*)(ao + 8192 * 64);
  unsigned int* w1b = wbo + 6144;
  unsigned int* w2b = w1b + 24576;
  unsigned int* wqb = w2b + 24576;

  k_qkv0<<<1024, 192, 0, stream>>>(weather, coords, W_emb, b_emb,
                                   W_qkv, b_qkv, gran, tidx,
                                   W_out, W1, W2,
                                   x, qbw, kbw, vtw, wbo, w1b, w2b, wqb);
  for (int l = 0; l < 3; ++l) {
    k_attn<<<1024, 512, 0, stream>>>(qbw, kbw, vtw, ao);
    if (l < 2) {
      k_fused<true, false><<<1024, 256, 0, stream>>>(
          x, ao, wbo + l * 2048, b_out + l * 64,
          g1 + l * 64, be1 + l * 64, w1b + l * 8192, b1 + l * 256,
          w2b + l * 8192, b2 + l * 64, g2 + l * 64, be2 + l * 64,
          wqb + l * 6144, b_qkv + (l + 1) * 192,
          gran + (l + 1) * 31 * 64, tidx, qbw, kbw, vtw,
          nullptr, nullptr, nullptr, x);
    } else {
      k_fused<false, true><<<1024, 256, 0, stream>>>(
          x, ao, wbo + l * 2048, b_out + l * 64,
          g1 + l * 64, be1 + l * 64, w1b + l * 8192, b1 + l * 256,
          w2b + l * 8192, b2 + l * 64, g2 + l * 64, be2 + l * 64,
          nullptr, nullptr, nullptr, nullptr, nullptr, nullptr, nullptr,
          W_fc, b_fc, out, nullptr);
    }
  }
}